// Round 9
// baseline (335.081 us; speedup 1.0000x reference)
//
#include <hip/hip_runtime.h>
#include <math.h>

#define SEQ 2048
#define CDIM 1536
#define HN 8
#define DVC 192
#define BN 2
#define NPOS 4095   // 2*SEQ-1
#define HDK 512     // H*DK
#define HDV 1536    // H*DV
#define PSTR 72     // Pbs LDS stride in halfs (144 B rows: 16B-aligned, 2-way banks max)

typedef __attribute__((ext_vector_type(8))) _Float16 hf8v;  // 8 f16 (4 VGPRs)
typedef __attribute__((ext_vector_type(4))) _Float16 hf4v;  // 4 f16 (b64)
typedef __attribute__((ext_vector_type(4))) float f4v;      // MFMA C/D frag

static __device__ __forceinline__ f4v mfma16(hf8v a, hf8v b, f4v c) {
  return __builtin_amdgcn_mfma_f32_16x16x32_f16(a, b, c, 0, 0, 0);
}
static __device__ __forceinline__ void gl2lds16(const void* g, void* l) {
  __builtin_amdgcn_global_load_lds((const __attribute__((address_space(1))) unsigned int*)g,
                                   (__attribute__((address_space(3))) unsigned int*)l,
                                   16, 0, 0);
}
// 16-lane (DPP row) max butterfly via row_ror — VALU pipe, replaces 4x ds_bpermute
static __device__ __forceinline__ float rowmax16(float x) {
  x = fmaxf(x, __int_as_float(__builtin_amdgcn_update_dpp(0, __float_as_int(x), 0x128, 0xf, 0xf, true)));
  x = fmaxf(x, __int_as_float(__builtin_amdgcn_update_dpp(0, __float_as_int(x), 0x124, 0xf, 0xf, true)));
  x = fmaxf(x, __int_as_float(__builtin_amdgcn_update_dpp(0, __float_as_int(x), 0x122, 0xf, 0xf, true)));
  x = fmaxf(x, __int_as_float(__builtin_amdgcn_update_dpp(0, __float_as_int(x), 0x121, 0xf, 0xf, true)));
  return x;
}

// ============ fused prep: cast x + 5 weight transposes + pe features ============
#define CAST_B 6144
#define TWQ_B  768
#define TWK_B  768
#define TWV_B  2304
#define TWO_B  2304
#define TWR_B  96
#define PE_B   1536
#define TW_END (CAST_B + TWQ_B + TWK_B + TWV_B + TWO_B + TWR_B)
#define PREP_BLOCKS (TW_END + PE_B)

__device__ __forceinline__ void twc_tile(const float* __restrict__ W, _Float16* __restrict__ WT,
                                         int K, int N, int tile, float (*tls)[33], int tid) {
  int ntn = N >> 5;
  int nt = tile % ntn, kt = tile / ntn;
  int k0 = kt * 32, n0 = nt * 32;
  int tx = tid & 31, ty = tid >> 5;
#pragma unroll
  for (int p = 0; p < 4; p++) tls[ty + p * 8][tx] = W[(size_t)(k0 + ty + p * 8) * N + n0 + tx];
  __syncthreads();
#pragma unroll
  for (int p = 0; p < 4; p++) {
    int n = ty + p * 8;
    WT[(size_t)(n0 + n) * K + k0 + tx] = (_Float16)tls[tx][n];
  }
}

__global__ __launch_bounds__(256) void prep_kernel(
    const float* __restrict__ x, const float* __restrict__ Wq, const float* __restrict__ Wk,
    const float* __restrict__ Wv, const float* __restrict__ Wo, const float* __restrict__ Wr,
    _Float16* __restrict__ xb, _Float16* __restrict__ WTqkv, _Float16* __restrict__ WoT,
    _Float16* __restrict__ WrT, _Float16* __restrict__ pe_h) {
  __shared__ float tls[32][33];
  int blk = blockIdx.x, tid = threadIdx.x;
  if (blk < CAST_B) {
    int i = (blk * 256 + tid) * 4;
    float4 v = *(const float4*)(x + i);
    _Float16 o[4] = {(_Float16)v.x, (_Float16)v.y, (_Float16)v.z, (_Float16)v.w};
    *(unsigned long long*)(xb + i) = *(const unsigned long long*)o;
  } else if (blk < CAST_B + TWQ_B) {
    twc_tile(Wq, WTqkv + 0 * (size_t)CDIM, CDIM, HDK, blk - CAST_B, tls, tid);
  } else if (blk < CAST_B + TWQ_B + TWK_B) {
    twc_tile(Wk, WTqkv + 512 * (size_t)CDIM, CDIM, HDK, blk - (CAST_B + TWQ_B), tls, tid);
  } else if (blk < CAST_B + TWQ_B + TWK_B + TWV_B) {
    twc_tile(Wv, WTqkv + 1024 * (size_t)CDIM, CDIM, HDV, blk - (CAST_B + TWQ_B + TWK_B), tls, tid);
  } else if (blk < CAST_B + TWQ_B + TWK_B + TWV_B + TWO_B) {
    twc_tile(Wo, WoT, CDIM, HDV, blk - (CAST_B + TWQ_B + TWK_B + TWV_B), tls, tid);
  } else if (blk < TW_END) {
    twc_tile(Wr, WrT, 192, HDK, blk - (CAST_B + TWQ_B + TWK_B + TWV_B + TWO_B), tls, tid);
  } else {
    // pe features [4096][192] f16; analytic gamma max (unimodal, mode=(conc-1)/rate)
    int idx = (blk - TW_END) * 256 + tid;  // over 4096*96
    int pos = idx / 96, f = idx - pos * 96;
    float val = 0.0f, sval = 0.0f;
    if (pos < NPOS) {
      float ap = fabsf((float)(pos - (SEQ - 1)));
      int j = f & 31, cls = f >> 5;
      if (cls == 0) {
        float hl = exp2f(3.0f + 8.0f * (float)j / 31.0f);
        val = exp2f(-ap / hl);
      } else if (cls == 1) {
        float cw = exp2f((float)(j + 1)) - 1.0f;
        val = (cw > ap) ? 1.0f : 0.0f;
      } else {
        float conc = 4.0f * (float)((j + 1) * (j + 1));
        float rate = (float)(j + 1) / 16.0f;
        float log_norm = lgammaf(conc) - conc * logf(rate);
        float pv = expf((conc - 1.0f) * logf(ap) - rate * ap - log_norm) + 1e-8f;
        float mode = (conc - 1.0f) / rate;
        float a0 = fminf(floorf(mode), 2047.0f);
        float a1 = fminf(a0 + 1.0f, 2047.0f);
        float p0 = expf((conc - 1.0f) * logf(a0) - rate * a0 - log_norm) + 1e-8f;
        float p1 = expf((conc - 1.0f) * logf(a1) - rate * a1 - log_norm) + 1e-8f;
        val = pv / fmaxf(p0, p1);
      }
      float sgn = (pos > SEQ - 1) ? 1.0f : ((pos < SEQ - 1) ? -1.0f : 0.0f);
      sval = sgn * val;
    }
    pe_h[pos * 192 + f] = (_Float16)val;
    pe_h[pos * 192 + 96 + f] = (_Float16)sval;
  }
}

// ========== fused QKV + RK GEMM, 128x128xBK64, XOR-swizzled LDS ==========
// blocks [0,640): QKV — A=xb, B=WTqkv, K=1536, ntx=20; epilogue:
//   c<512 -> qb*0.125 ; c<1024 -> kb[B,H,S,64] ; else vtb[B,H,192,S] PI-PERMUTED
// blocks [640,768): RK — A=pe_h, B=WrT, K=192, ntx=4; rkb[(h*4096+pos)*64+d]
// Per-segment bijective XCD band swizzle (both segment sizes divisible by 8).
__global__ __launch_bounds__(256, 3) void mfma_gemm_qkvrk(
    const _Float16* __restrict__ xb, const _Float16* __restrict__ WTqkv,
    const _Float16* __restrict__ pe_h, const _Float16* __restrict__ WrT,
    _Float16* __restrict__ qb, _Float16* __restrict__ kb, _Float16* __restrict__ vtb,
    _Float16* __restrict__ rkb) {
  __shared__ __align__(16) _Float16 As[128 * 64];
  __shared__ __align__(16) _Float16 Bs[128 * 64];
  const int tid = threadIdx.x;
  const int lane = tid & 63, l15 = lane & 15, quad = lane >> 4;
  const int wv = tid >> 6;
  const int wm = (wv & 1) * 64, wn = (wv >> 1) * 64;
  const bool isrk = blockIdx.x >= 640;
  const _Float16* A;
  const _Float16* B;
  int K, ntx, lin, cpx;
  if (!isrk) {
    A = xb; B = WTqkv; K = CDIM; ntx = 20; lin = blockIdx.x; cpx = 80;
  } else {
    A = pe_h; B = WrT; K = 192; ntx = 4; lin = blockIdx.x - 640; cpx = 16;
  }
  const int sw = (lin & 7) * cpx + (lin >> 3);
  const int row0 = (sw / ntx) * 128, col0 = (sw % ntx) * 128;
  f4v acc[4][4];
#pragma unroll
  for (int i = 0; i < 4; i++)
#pragma unroll
    for (int j = 0; j < 4; j++) acc[i][j] = (f4v)0.0f;

  for (int k0 = 0; k0 < K; k0 += 64) {
    __syncthreads();
#pragma unroll
    for (int p = 0; p < 4; p++) {
      int idx = tid + p * 256;
      int rr = idx >> 3, sc = idx & 7;
      int gc = (sc ^ (rr & 7)) << 3;
      gl2lds16(A + (size_t)(row0 + rr) * K + k0 + gc, As + idx * 8);
      gl2lds16(B + (size_t)(col0 + rr) * K + k0 + gc, Bs + idx * 8);
    }
    __syncthreads();
#pragma unroll
    for (int kc = 0; kc < 2; kc++) {
      hf8v af[4], bfr[4];
#pragma unroll
      for (int t = 0; t < 4; t++) {
        int lrA = wm + t * 16 + l15;
        int lrB = wn + t * 16 + l15;
        af[t]  = *(const hf8v*)(As + lrA * 64 + ((((kc << 2) | quad) ^ (lrA & 7)) << 3));
        bfr[t] = *(const hf8v*)(Bs + lrB * 64 + ((((kc << 2) | quad) ^ (lrB & 7)) << 3));
      }
#pragma unroll
      for (int mt = 0; mt < 4; mt++)
#pragma unroll
        for (int nt = 0; nt < 4; nt++)
          acc[mt][nt] = mfma16(af[mt], bfr[nt], acc[mt][nt]);
    }
  }
#pragma unroll
  for (int mt = 0; mt < 4; mt++)
#pragma unroll
    for (int reg = 0; reg < 4; reg++) {
      int r = row0 + wm + mt * 16 + quad * 4 + reg;
      int bb = r >> 11, ss = r & (SEQ - 1);
#pragma unroll
      for (int nt = 0; nt < 4; nt++) {
        int c = col0 + wn + nt * 16 + l15;
        float vv = acc[mt][nt][reg];
        if (!isrk) {
          if (c < 512) {
            qb[(size_t)r * HDK + c] = (_Float16)(vv * 0.125f);
          } else if (c < 1024) {
            int cc = c - 512, h = cc >> 6, d = cc & 63;
            kb[(((size_t)bb * HN + h) * SEQ + ss) * 64 + d] = (_Float16)vv;
          } else {
            int cc = c - 1024, h = cc / DVC, e = cc - h * DVC;
            // pi-permute key within its 64-block: key k -> pos (k&15)*4 + ((k>>4)&3)
            int jp = (ss & ~63) | ((ss & 15) << 2) | ((ss >> 4) & 3);
            vtb[(((size_t)bb * HN + h) * DVC + e) * SEQ + jp] = (_Float16)vv;
          }
        } else {
          int h = c >> 6, d = c & 63;
          rkb[((size_t)h * 4096 + r) * 64 + d] = (_Float16)vv;
        }
      }
    }
}

// ======== output GEMM: 64x128xBK64 tile -> 768 blocks = 3 blocks/CU resident ========
__global__ __launch_bounds__(256, 3) void mfma_gemm_out(
    const _Float16* __restrict__ A, const _Float16* __restrict__ B,
    const float* __restrict__ bias, float* __restrict__ out) {
  __shared__ __align__(16) _Float16 As[64 * 64];
  __shared__ __align__(16) _Float16 Bs[128 * 64];
  const int K = CDIM, ntx = 12;
  const int tid = threadIdx.x;
  const int lane = tid & 63, l15 = lane & 15, quad = lane >> 4;
  const int wv = tid >> 6;
  const int wm = (wv & 1) * 32, wn = (wv >> 1) * 64;
  const int lin = blockIdx.x;
  const int cpx = gridDim.x >> 3;  // 96
  const int sw = (lin & 7) * cpx + (lin >> 3);
  const int row0 = (sw / ntx) * 64, col0 = (sw % ntx) * 128;
  f4v acc[2][4];
#pragma unroll
  for (int i = 0; i < 2; i++)
#pragma unroll
    for (int j = 0; j < 4; j++) acc[i][j] = (f4v)0.0f;

  for (int k0 = 0; k0 < K; k0 += 64) {
    __syncthreads();
#pragma unroll
    for (int p = 0; p < 2; p++) {
      int idx = tid + p * 256;
      int rr = idx >> 3, sc = idx & 7;
      int gc = (sc ^ (rr & 7)) << 3;
      gl2lds16(A + (size_t)(row0 + rr) * K + k0 + gc, As + idx * 8);
    }
#pragma unroll
    for (int p = 0; p < 4; p++) {
      int idx = tid + p * 256;
      int rr = idx >> 3, sc = idx & 7;
      int gc = (sc ^ (rr & 7)) << 3;
      gl2lds16(B + (size_t)(col0 + rr) * K + k0 + gc, Bs + idx * 8);
    }
    __syncthreads();
#pragma unroll
    for (int kc = 0; kc < 2; kc++) {
      hf8v af[2], bfr[4];
#pragma unroll
      for (int t = 0; t < 2; t++) {
        int lrA = wm + t * 16 + l15;
        af[t] = *(const hf8v*)(As + lrA * 64 + ((((kc << 2) | quad) ^ (lrA & 7)) << 3));
      }
#pragma unroll
      for (int t = 0; t < 4; t++) {
        int lrB = wn + t * 16 + l15;
        bfr[t] = *(const hf8v*)(Bs + lrB * 64 + ((((kc << 2) | quad) ^ (lrB & 7)) << 3));
      }
#pragma unroll
      for (int mt = 0; mt < 2; mt++)
#pragma unroll
        for (int nt = 0; nt < 4; nt++)
          acc[mt][nt] = mfma16(af[mt], bfr[nt], acc[mt][nt]);
    }
  }
#pragma unroll
  for (int mt = 0; mt < 2; mt++)
#pragma unroll
    for (int reg = 0; reg < 4; reg++) {
      int r = row0 + wm + mt * 16 + quad * 4 + reg;
#pragma unroll
      for (int nt = 0; nt < 4; nt++) {
        int c = col0 + wn + nt * 16 + l15;
        out[(size_t)r * HDV + c] = acc[mt][nt][reg] + bias[c];
      }
    }
}

// ================= flash MFMA attention: ROTATED staging pipeline ==============
// 256 threads, 4 waves x 2 strips, (256,2), 2 blocks/CU, XCD swizzle.
// Rotation: tile j+1's mask/K/RK issued after the barrier ending tile j's
// QK-phase reads (latency hides under PV); V(j+1) issued after the PV-read
// barrier (latency hides under next QK/softmax). 3 barriers/iter, same as
// before, but no exposed staging latency.
// Per-wave vmcnt: top-of-iter outstanding = V(j)=6 -> vmcnt(0) pre-PV-barrier;
// after issuing mask4+K2+RK6 then V6, vmcnt(6) drains the 12 older ops (FIFO).
template <bool SPLITKV>
__global__ __launch_bounds__(256, 2) void attn_mfma(
    const _Float16* __restrict__ qb, const _Float16* __restrict__ kb,
    const _Float16* __restrict__ vtb, const _Float16* __restrict__ rkb,
    const float* __restrict__ rwb, const int* __restrict__ mask,
    _Float16* __restrict__ attn_out, float* __restrict__ Opart, float* __restrict__ ml) {
  __shared__ __align__(16) _Float16 Vts[192 * 64];   // 24576 B (pi-permuted keys)
  __shared__ __align__(16) _Float16 RKs[192 * 64];   // 24576 B
  __shared__ __align__(16) _Float16 Kts[64 * 64];    //  8192 B
  __shared__ __align__(16) _Float16 Pbs[128 * PSTR]; // 18432 B, wave-private (NOT aliased)
  // total 75776 B -> 2 blocks/CU

  const int lin = blockIdx.x;
  const int chunk = SPLITKV ? 64 : 32;            // blocks per XCD
  const int swz = (lin & 7) * chunk + (lin >> 3); // bijective: same-by -> same XCD
  const int bx = swz & 15;
  const int by = swz >> 4;
  const int i0 = bx * 128;
  const int bh = SPLITKV ? (by & 15) : by;
  const int half = SPLITKV ? (by >> 4) : 0;
  const int b = bh >> 3, h = bh & 7;
  const int tid = threadIdx.x;
  const int wv = tid >> 6, lane = tid & 63;
  const int l15 = lane & 15, quad = lane >> 4;

  // Q A-fragments, 2 strips (held in VGPRs across all key tiles)
  hf8v qf[2][2], qbf[2][2];
#pragma unroll
  for (int s = 0; s < 2; s++) {
    int qrow = i0 + wv * 32 + s * 16 + l15;
    const _Float16* qp = qb + (size_t)(b * SEQ + qrow) * HDK + h * 64;
#pragma unroll
    for (int kc = 0; kc < 2; kc++) {
      hf8v qv = *(const hf8v*)(qp + kc * 32 + quad * 8);
      qf[s][kc] = qv;
      hf8v t;
#pragma unroll
      for (int j = 0; j < 8; j++)
        t[j] = (_Float16)((float)qv[j] + rwb[h * 64 + kc * 32 + quad * 8 + j]);
      qbf[s][kc] = t;
    }
  }

  f4v Of[2][12];
#pragma unroll
  for (int s = 0; s < 2; s++)
#pragma unroll
    for (int se = 0; se < 12; se++) Of[s][se] = (f4v)0.0f;
  float m_i[2][4] = {{-INFINITY, -INFINITY, -INFINITY, -INFINITY},
                     {-INFINITY, -INFINITY, -INFINITY, -INFINITY}};
  float l_i[2][4] = {{0.f, 0.f, 0.f, 0.f}, {0.f, 0.f, 0.f, 0.f}};  // per-lane partials

  const int j0beg = SPLITKV ? half * (SEQ / 2) : 0;
  const int j0end = SPLITKV ? j0beg + SEQ / 2 : SEQ;

  int mraw[4];
  // ---- prologue: stage tile 0 (mask, K, RK, then V); drain mask/K/RK, leave V
  {
    const int j0 = j0beg;
#pragma unroll
    for (int st = 0; st < 4; st++) mraw[st] = mask[b * SEQ + j0 + st * 16 + l15];
    const int U0 = j0 - i0 + 1920;
#pragma unroll
    for (int r = 0; r < 2; r++) {
      int idx = tid + r * 256, row = idx >> 3, sc = idx & 7;
      gl2lds16(kb + ((size_t)bh * SEQ + j0 + row) * 64 + ((sc ^ (row & 7)) << 3), Kts + idx * 8);
    }
#pragma unroll
    for (int r = 0; r < 6; r++) {
      int idx = tid + r * 256, row = idx >> 3, sc = idx & 7;
      gl2lds16(rkb + ((size_t)h * 4096 + U0 + row) * 64 + ((sc ^ (row & 7)) << 3), RKs + idx * 8);
    }
#pragma unroll
    for (int r = 0; r < 6; r++) {
      int idx = tid + r * 256, row = idx >> 3, sc = idx & 7;
      gl2lds16(vtb + ((size_t)bh * DVC + row) * SEQ + j0 + ((sc ^ (row & 7)) << 3), Vts + idx * 8);
    }
    asm volatile("s_waitcnt vmcnt(6)" ::: "memory");
    __builtin_amdgcn_s_barrier();
    __builtin_amdgcn_sched_barrier(0);
  }

  for (int j0 = j0beg; j0 < j0end; j0 += 64) {
    const bool notlast = (j0 + 64 < j0end);
    float mv[4];
#pragma unroll
    for (int st = 0; st < 4; st++) mv[st] = mraw[st] ? 0.f : -1e9f;

#pragma unroll
    for (int s = 0; s < 2; s++) {
      // content logits
      __builtin_amdgcn_s_setprio(1);
      f4v Sf[4];
#pragma unroll
      for (int st = 0; st < 4; st++) {
        Sf[st] = (f4v)0.0f;
#pragma unroll
        for (int kc = 0; kc < 2; kc++) {
          int row = st * 16 + l15;
          hf8v kf = *(const hf8v*)(Kts + row * 64 + ((((kc << 2) | quad) ^ (row & 7)) << 3));
          Sf[st] = mfma16(qf[s][kc], kf, Sf[st]);
        }
      }
      // rel logits over 80-row window
      f4v Rf[5];
      const int tb = 112 - 32 * wv - 16 * s;
#pragma unroll
      for (int u = 0; u < 5; u++) {
        Rf[u] = (f4v)0.0f;
#pragma unroll
        for (int kc = 0; kc < 2; kc++) {
          int row = tb + u * 16 + l15;
          hf8v rf = *(const hf8v*)(RKs + row * 64 + ((((kc << 2) | quad) ^ (row & 7)) << 3));
          Rf[u] = mfma16(qbf[s][kc], rf, Rf[u]);
        }
      }
      __builtin_amdgcn_s_setprio(0);
      // band extraction via bpermute: S[r][c] += R[r][c-r+15]
#pragma unroll
      for (int reg = 0; reg < 4; reg++) {
        int delta = l15 - (quad << 2) - reg + 15;  // [0,30]
        int srcl = (quad << 4) | (delta & 15);
        float sh0 = __shfl(Rf[0][reg], srcl, 64);
        float sh1 = __shfl(Rf[1][reg], srcl, 64);
        float sh2 = __shfl(Rf[2][reg], srcl, 64);
        float sh3 = __shfl(Rf[3][reg], srcl, 64);
        float sh4 = __shfl(Rf[4][reg], srcl, 64);
        bool hib = delta >= 16;
        Sf[0][reg] += (hib ? sh1 : sh0) + mv[0];
        Sf[1][reg] += (hib ? sh2 : sh1) + mv[1];
        Sf[2][reg] += (hib ? sh3 : sh2) + mv[2];
        Sf[3][reg] += (hib ? sh4 : sh3) + mv[3];
      }
      // online softmax with defer-max (THR=8): row-max via DPP (VALU, not LDS);
      // rescale only when max grows by >8 -> P bounded by e^8 (fits f16).
#pragma unroll
      for (int reg = 0; reg < 4; reg++) {
        float t = fmaxf(fmaxf(Sf[0][reg], Sf[1][reg]), fmaxf(Sf[2][reg], Sf[3][reg]));
        t = rowmax16(t);
        if (__any(t - m_i[s][reg] > 8.0f)) {
          float mn = fmaxf(m_i[s][reg], t);
          float alpha = __expf(m_i[s][reg] - mn);
          m_i[s][reg] = mn;
          l_i[s][reg] *= alpha;
#pragma unroll
          for (int se = 0; se < 12; se++) Of[s][se][reg] *= alpha;
        }
        float mcur = m_i[s][reg];
        hf4v pv;
        float rs = 0.f;
#pragma unroll
        for (int st = 0; st < 4; st++) {
          float p = __expf(Sf[st][reg] - mcur);
          rs += p;
          pv[st] = (_Float16)p;
        }
        l_i[s][reg] += rs;  // per-lane partial; row-reduce in epilogue
        *(hf4v*)(Pbs + (size_t)(wv * 32 + s * 16 + quad * 4 + reg) * PSTR + l15 * 4) = pv;
      }
    }

    // P A-frags (wave-private LDS, same-wave in-order DS)
    hf8v pa[2][2];
#pragma unroll
    for (int s = 0; s < 2; s++)
#pragma unroll
      for (int kc = 0; kc < 2; kc++)
        pa[s][kc] = *(const hf8v*)(Pbs + (size_t)(wv * 32 + s * 16 + l15) * PSTR +
                                   kc * 32 + quad * 8);
    // drain own V(j); barrier joins: Vts ready everywhere AND all waves past
    // their Kts/RKs reads -> safe to overwrite Kts/RKs after this barrier.
    asm volatile("s_waitcnt vmcnt(0)" ::: "memory");
    __builtin_amdgcn_s_barrier();
    __builtin_amdgcn_sched_barrier(0);

    if (notlast) {
      const int j1 = j0 + 64;
#pragma unroll
      for (int st = 0; st < 4; st++) mraw[st] = mask[b * SEQ + j1 + st * 16 + l15];
      const int U1 = j1 - i0 + 1920;
#pragma unroll
      for (int r = 0; r < 2; r++) {
        int idx = tid + r * 256, row = idx >> 3, sc = idx & 7;
        gl2lds16(kb + ((size_t)bh * SEQ + j1 + row) * 64 + ((sc ^ (row & 7)) << 3), Kts + idx * 8);
      }
#pragma unroll
      for (int r = 0; r < 6; r++) {
        int idx = tid + r * 256, row = idx >> 3, sc = idx & 7;
        gl2lds16(rkb + ((size_t)h * 4096 + U1 + row) * 64 + ((sc ^ (row & 7)) << 3), RKs + idx * 8);
      }
    }

    // PV: V B-frags from Vts (pi-ordered keys); K/RK(j+1) latency hides here
    __builtin_amdgcn_s_setprio(1);
#pragma unroll
    for (int se = 0; se < 12; se++) {
#pragma unroll
      for (int kc = 0; kc < 2; kc++) {
        int row = se * 16 + l15;
        hf8v vf = *(const hf8v*)(Vts + row * 64 + ((((kc << 2) | quad) ^ (row & 7)) << 3));
        Of[0][se] = mfma16(pa[0][kc], vf, Of[0][se]);
        Of[1][se] = mfma16(pa[1][kc], vf, Of[1][se]);
      }
    }
    __builtin_amdgcn_s_setprio(0);

    if (notlast) {
      const int j1 = j0 + 64;
      // all waves done reading Vts -> safe to overwrite
      __builtin_amdgcn_s_barrier();
      __builtin_amdgcn_sched_barrier(0);
#pragma unroll
      for (int r = 0; r < 6; r++) {
        int idx = tid + r * 256, row = idx >> 3, sc = idx & 7;
        gl2lds16(vtb + ((size_t)bh * DVC + row) * SEQ + j1 + ((sc ^ (row & 7)) << 3), Vts + idx * 8);
      }
      // drain mask/K/RK(j+1) (12 older ops), leave V(j+1)=6 in flight; join.
      asm volatile("s_waitcnt vmcnt(6)" ::: "memory");
      __builtin_amdgcn_s_barrier();
      __builtin_amdgcn_sched_barrier(0);
    }
  }

#pragma unroll
  for (int s = 0; s < 2; s++)
#pragma unroll
    for (int reg = 0; reg < 4; reg++) {
      float ls = l_i[s][reg];
      ls += __shfl_xor(ls, 1);
      ls += __shfl_xor(ls, 2);
      ls += __shfl_xor(ls, 4);
      ls += __shfl_xor(ls, 8);
      int row = i0 + wv * 32 + s * 16 + quad * 4 + reg;
      int rg = b * SEQ + row;
      if constexpr (SPLITKV) {
        float* Op = Opart + ((size_t)(half * 4096 + rg)) * HDV + h * DVC;
#pragma unroll
        for (int se = 0; se < 12; se++) Op[se * 16 + l15] = Of[s][se][reg];
        if (l15 == 0) {
          size_t mlb = (((size_t)half * 4096 + rg) * HN + h) * 2;
          ml[mlb] = m_i[s][reg];
          ml[mlb + 1] = ls;
        }
      } else {
        float inv = 1.0f / ls;
        size_t base2 = (size_t)rg * HDV + h * DVC;
#pragma unroll
        for (int se = 0; se < 12; se++)
          attn_out[base2 + se * 16 + l15] = (_Float16)(Of[s][se][reg] * inv);
      }
    }
}

// ================= combine the two KV halves =================
__global__ __launch_bounds__(256) void combine_kernel(const float* __restrict__ Opart,
                                                      const float* __restrict__ ml,
                                                      _Float16* __restrict__ attn_out) {
  int i4 = blockIdx.x * 256 + threadIdx.x;  // over 4096*384
  int rg = i4 / 384, c4 = (i4 - rg * 384) * 4;
  int h = c4 / DVC;
  size_t mlb0 = ((size_t)rg * HN + h) * 2;
  size_t mlb1 = (((size_t)4096 + rg) * HN + h) * 2;
  float m0 = ml[mlb0], l0 = ml[mlb0 + 1];
  float m1 = ml[mlb1], l1 = ml[mlb1 + 1];
  float M = fmaxf(m0, m1);
  float w0 = __expf(m0 - M), w1 = __expf(m1 - M);
  float inv = 1.0f / (l0 * w0 + l1 * w1);
  float4 O0 = *(const float4*)(Opart + (size_t)rg * HDV + c4);
  float4 O1 = *(const float4*)(Opart + ((size_t)4096 + rg) * HDV + c4);
  _Float16 o[4] = {(_Float16)((O0.x * w0 + O1.x * w1) * inv),
                   (_Float16)((O0.y * w0 + O1.y * w1) * inv),
                   (_Float16)((O0.z * w0 + O1.z * w1) * inv),
                   (_Float16)((O0.w * w0 + O1.w * w1) * inv)};
  *(unsigned long long*)(attn_out + (size_t)rg * HDV + c4) = *(const unsigned long long*)o;
}

extern "C" void kernel_launch(void* const* d_in, const int* in_sizes, int n_in,
                              void* d_out, int out_size, void* d_ws, size_t ws_size,
                              hipStream_t stream) {
  const float* x    = (const float*)d_in[0];
  const int*   mask = (const int*)d_in[1];
  const float* Wq   = (const float*)d_in[2];
  const float* Wk   = (const float*)d_in[3];
  const float* Wv   = (const float*)d_in[4];
  const float* Wr   = (const float*)d_in[5];
  const float* rwb  = (const float*)d_in[6];
  const float* Wo   = (const float*)d_in[7];
  const float* bo   = (const float*)d_in[8];
  float* out = (float*)d_out;

  char* wsb = (char*)d_ws;
  size_t o = 0;
  auto al = [](size_t v) { return (v + 255) & ~(size_t)255; };
#define CARVE(ptr_t, name, bytes) ptr_t name = (ptr_t)(wsb + o); o = al(o + (bytes));
  CARVE(_Float16*, pe_h, (size_t)4096 * 192 * 2)
  CARVE(_Float16*, WrT, (size_t)HDK * 192 * 2)
  CARVE(_Float16*, xb, (size_t)BN * SEQ * CDIM * 2)
  CARVE(_Float16*, WTqkv, (size_t)2560 * CDIM * 2)
  CARVE(_Float16*, WoT, (size_t)HDV * CDIM * 2)
  CARVE(_Float16*, qb, (size_t)BN * SEQ * HDK * 2)
  CARVE(_Float16*, kb, (size_t)BN * SEQ * HDK * 2)
  CARVE(_Float16*, vtb, (size_t)BN * SEQ * HDV * 2)
  CARVE(_Float16*, rkb, (size_t)HN * 4096 * 64 * 2)
  _Float16* attnh = xb;  // xb dead after QKV gemm -> safe alias
  CARVE(float*, Opart, (size_t)2 * 4096 * HDV * 4)
  CARVE(float*, ml, (size_t)2 * 4096 * HN * 2 * 4)
  bool dosplit = (o <= ws_size);

  prep_kernel<<<PREP_BLOCKS, 256, 0, stream>>>(x, Wq, Wk, Wv, Wo, Wr, xb, WTqkv, WoT, WrT,
                                               pe_h);
  mfma_gemm_qkvrk<<<768, 256, 0, stream>>>(xb, WTqkv, pe_h, WrT, qb, kb, vtb, rkb);
  if (dosplit) {
    attn_mfma<true><<<512, 256, 0, stream>>>(qb, kb, vtb, rkb, rwb, mask,
                                             attnh, Opart, ml);
    combine_kernel<<<4096 * 384 / 256, 256, 0, stream>>>(Opart, ml, attnh);
  } else {
    attn_mfma<false><<<256, 256, 0, stream>>>(qb, kb, vtb, rkb, rwb, mask,
                                              attnh, nullptr, nullptr);
  }
  mfma_gemm_out<<<768, 256, 0, stream>>>(attnh, WoT, bo, out);
}

// Round 10
// 299.993 us; speedup vs baseline: 1.1170x; 1.1170x over previous
//
#include <hip/hip_runtime.h>
#include <math.h>

#define SEQ 2048
#define CDIM 1536
#define HN 8
#define DVC 192
#define BN 2
#define NPOS 4095   // 2*SEQ-1
#define HDK 512     // H*DK
#define HDV 1536    // H*DV
#define PSTR 72     // Pbs LDS stride in halfs (144 B rows: 16B-aligned, 2-way banks max)

typedef __attribute__((ext_vector_type(8))) _Float16 hf8v;  // 8 f16 (4 VGPRs)
typedef __attribute__((ext_vector_type(4))) _Float16 hf4v;  // 4 f16 (b64)
typedef __attribute__((ext_vector_type(4))) float f4v;      // MFMA C/D frag

static __device__ __forceinline__ f4v mfma16(hf8v a, hf8v b, f4v c) {
  return __builtin_amdgcn_mfma_f32_16x16x32_f16(a, b, c, 0, 0, 0);
}
static __device__ __forceinline__ void gl2lds16(const void* g, void* l) {
  __builtin_amdgcn_global_load_lds((const __attribute__((address_space(1))) unsigned int*)g,
                                   (__attribute__((address_space(3))) unsigned int*)l,
                                   16, 0, 0);
}
// 16-lane (DPP row) max butterfly via row_ror — VALU pipe, replaces 4x ds_bpermute
static __device__ __forceinline__ float rowmax16(float x) {
  x = fmaxf(x, __int_as_float(__builtin_amdgcn_update_dpp(0, __float_as_int(x), 0x128, 0xf, 0xf, true)));
  x = fmaxf(x, __int_as_float(__builtin_amdgcn_update_dpp(0, __float_as_int(x), 0x124, 0xf, 0xf, true)));
  x = fmaxf(x, __int_as_float(__builtin_amdgcn_update_dpp(0, __float_as_int(x), 0x122, 0xf, 0xf, true)));
  x = fmaxf(x, __int_as_float(__builtin_amdgcn_update_dpp(0, __float_as_int(x), 0x121, 0xf, 0xf, true)));
  return x;
}

// ============ fused prep: cast x + 5 weight transposes + pe features ============
#define CAST_B 6144
#define TWQ_B  768
#define TWK_B  768
#define TWV_B  2304
#define TWO_B  2304
#define TWR_B  96
#define PE_B   1536
#define TW_END (CAST_B + TWQ_B + TWK_B + TWV_B + TWO_B + TWR_B)
#define PREP_BLOCKS (TW_END + PE_B)

__device__ __forceinline__ void twc_tile(const float* __restrict__ W, _Float16* __restrict__ WT,
                                         int K, int N, int tile, float (*tls)[33], int tid) {
  int ntn = N >> 5;
  int nt = tile % ntn, kt = tile / ntn;
  int k0 = kt * 32, n0 = nt * 32;
  int tx = tid & 31, ty = tid >> 5;
#pragma unroll
  for (int p = 0; p < 4; p++) tls[ty + p * 8][tx] = W[(size_t)(k0 + ty + p * 8) * N + n0 + tx];
  __syncthreads();
#pragma unroll
  for (int p = 0; p < 4; p++) {
    int n = ty + p * 8;
    WT[(size_t)(n0 + n) * K + k0 + tx] = (_Float16)tls[tx][n];
  }
}

__global__ __launch_bounds__(256) void prep_kernel(
    const float* __restrict__ x, const float* __restrict__ Wq, const float* __restrict__ Wk,
    const float* __restrict__ Wv, const float* __restrict__ Wo, const float* __restrict__ Wr,
    _Float16* __restrict__ xb, _Float16* __restrict__ WTqkv, _Float16* __restrict__ WoT,
    _Float16* __restrict__ WrT, _Float16* __restrict__ pe_h) {
  __shared__ float tls[32][33];
  int blk = blockIdx.x, tid = threadIdx.x;
  if (blk < CAST_B) {
    int i = (blk * 256 + tid) * 4;
    float4 v = *(const float4*)(x + i);
    _Float16 o[4] = {(_Float16)v.x, (_Float16)v.y, (_Float16)v.z, (_Float16)v.w};
    *(unsigned long long*)(xb + i) = *(const unsigned long long*)o;
  } else if (blk < CAST_B + TWQ_B) {
    twc_tile(Wq, WTqkv + 0 * (size_t)CDIM, CDIM, HDK, blk - CAST_B, tls, tid);
  } else if (blk < CAST_B + TWQ_B + TWK_B) {
    twc_tile(Wk, WTqkv + 512 * (size_t)CDIM, CDIM, HDK, blk - (CAST_B + TWQ_B), tls, tid);
  } else if (blk < CAST_B + TWQ_B + TWK_B + TWV_B) {
    twc_tile(Wv, WTqkv + 1024 * (size_t)CDIM, CDIM, HDV, blk - (CAST_B + TWQ_B + TWK_B), tls, tid);
  } else if (blk < CAST_B + TWQ_B + TWK_B + TWV_B + TWO_B) {
    twc_tile(Wo, WoT, CDIM, HDV, blk - (CAST_B + TWQ_B + TWK_B + TWV_B), tls, tid);
  } else if (blk < TW_END) {
    twc_tile(Wr, WrT, 192, HDK, blk - (CAST_B + TWQ_B + TWK_B + TWV_B + TWO_B), tls, tid);
  } else {
    // pe features [4096][192] f16; analytic gamma max (unimodal, mode=(conc-1)/rate)
    int idx = (blk - TW_END) * 256 + tid;  // over 4096*96
    int pos = idx / 96, f = idx - pos * 96;
    float val = 0.0f, sval = 0.0f;
    if (pos < NPOS) {
      float ap = fabsf((float)(pos - (SEQ - 1)));
      int j = f & 31, cls = f >> 5;
      if (cls == 0) {
        float hl = exp2f(3.0f + 8.0f * (float)j / 31.0f);
        val = exp2f(-ap / hl);
      } else if (cls == 1) {
        float cw = exp2f((float)(j + 1)) - 1.0f;
        val = (cw > ap) ? 1.0f : 0.0f;
      } else {
        float conc = 4.0f * (float)((j + 1) * (j + 1));
        float rate = (float)(j + 1) / 16.0f;
        float log_norm = lgammaf(conc) - conc * logf(rate);
        float pv = expf((conc - 1.0f) * logf(ap) - rate * ap - log_norm) + 1e-8f;
        float mode = (conc - 1.0f) / rate;
        float a0 = fminf(floorf(mode), 2047.0f);
        float a1 = fminf(a0 + 1.0f, 2047.0f);
        float p0 = expf((conc - 1.0f) * logf(a0) - rate * a0 - log_norm) + 1e-8f;
        float p1 = expf((conc - 1.0f) * logf(a1) - rate * a1 - log_norm) + 1e-8f;
        val = pv / fmaxf(p0, p1);
      }
      float sgn = (pos > SEQ - 1) ? 1.0f : ((pos < SEQ - 1) ? -1.0f : 0.0f);
      sval = sgn * val;
    }
    pe_h[pos * 192 + f] = (_Float16)val;
    pe_h[pos * 192 + 96 + f] = (_Float16)sval;
  }
}

// ========== fused QKV + RK GEMM, 128x128xBK64, XOR-swizzled LDS ==========
// blocks [0,640): QKV — A=xb, B=WTqkv, K=1536, ntx=20; epilogue:
//   c<512 -> qb*0.125 ; c<1024 -> kb[B,H,S,64] ; else vtb[B,H,192,S] PI-PERMUTED
// blocks [640,768): RK — A=pe_h, B=WrT, K=192, ntx=4; rkb[(h*4096+pos)*64+d]
// Per-segment bijective XCD band swizzle (both segment sizes divisible by 8).
__global__ __launch_bounds__(256, 3) void mfma_gemm_qkvrk(
    const _Float16* __restrict__ xb, const _Float16* __restrict__ WTqkv,
    const _Float16* __restrict__ pe_h, const _Float16* __restrict__ WrT,
    _Float16* __restrict__ qb, _Float16* __restrict__ kb, _Float16* __restrict__ vtb,
    _Float16* __restrict__ rkb) {
  __shared__ __align__(16) _Float16 As[128 * 64];
  __shared__ __align__(16) _Float16 Bs[128 * 64];
  const int tid = threadIdx.x;
  const int lane = tid & 63, l15 = lane & 15, quad = lane >> 4;
  const int wv = tid >> 6;
  const int wm = (wv & 1) * 64, wn = (wv >> 1) * 64;
  const bool isrk = blockIdx.x >= 640;
  const _Float16* A;
  const _Float16* B;
  int K, ntx, lin, cpx;
  if (!isrk) {
    A = xb; B = WTqkv; K = CDIM; ntx = 20; lin = blockIdx.x; cpx = 80;
  } else {
    A = pe_h; B = WrT; K = 192; ntx = 4; lin = blockIdx.x - 640; cpx = 16;
  }
  const int sw = (lin & 7) * cpx + (lin >> 3);
  const int row0 = (sw / ntx) * 128, col0 = (sw % ntx) * 128;
  f4v acc[4][4];
#pragma unroll
  for (int i = 0; i < 4; i++)
#pragma unroll
    for (int j = 0; j < 4; j++) acc[i][j] = (f4v)0.0f;

  for (int k0 = 0; k0 < K; k0 += 64) {
    __syncthreads();
#pragma unroll
    for (int p = 0; p < 4; p++) {
      int idx = tid + p * 256;
      int rr = idx >> 3, sc = idx & 7;
      int gc = (sc ^ (rr & 7)) << 3;
      gl2lds16(A + (size_t)(row0 + rr) * K + k0 + gc, As + idx * 8);
      gl2lds16(B + (size_t)(col0 + rr) * K + k0 + gc, Bs + idx * 8);
    }
    __syncthreads();
#pragma unroll
    for (int kc = 0; kc < 2; kc++) {
      hf8v af[4], bfr[4];
#pragma unroll
      for (int t = 0; t < 4; t++) {
        int lrA = wm + t * 16 + l15;
        int lrB = wn + t * 16 + l15;
        af[t]  = *(const hf8v*)(As + lrA * 64 + ((((kc << 2) | quad) ^ (lrA & 7)) << 3));
        bfr[t] = *(const hf8v*)(Bs + lrB * 64 + ((((kc << 2) | quad) ^ (lrB & 7)) << 3));
      }
#pragma unroll
      for (int mt = 0; mt < 4; mt++)
#pragma unroll
        for (int nt = 0; nt < 4; nt++)
          acc[mt][nt] = mfma16(af[mt], bfr[nt], acc[mt][nt]);
    }
  }
#pragma unroll
  for (int mt = 0; mt < 4; mt++)
#pragma unroll
    for (int reg = 0; reg < 4; reg++) {
      int r = row0 + wm + mt * 16 + quad * 4 + reg;
      int bb = r >> 11, ss = r & (SEQ - 1);
#pragma unroll
      for (int nt = 0; nt < 4; nt++) {
        int c = col0 + wn + nt * 16 + l15;
        float vv = acc[mt][nt][reg];
        if (!isrk) {
          if (c < 512) {
            qb[(size_t)r * HDK + c] = (_Float16)(vv * 0.125f);
          } else if (c < 1024) {
            int cc = c - 512, h = cc >> 6, d = cc & 63;
            kb[(((size_t)bb * HN + h) * SEQ + ss) * 64 + d] = (_Float16)vv;
          } else {
            int cc = c - 1024, h = cc / DVC, e = cc - h * DVC;
            // pi-permute key within its 64-block: key k -> pos (k&15)*4 + ((k>>4)&3)
            int jp = (ss & ~63) | ((ss & 15) << 2) | ((ss >> 4) & 3);
            vtb[(((size_t)bb * HN + h) * DVC + e) * SEQ + jp] = (_Float16)vv;
          }
        } else {
          int h = c >> 6, d = c & 63;
          rkb[((size_t)h * 4096 + r) * 64 + d] = (_Float16)vv;
        }
      }
    }
}

// ======== output GEMM: 64x128xBK64 tile -> 768 blocks = 3 blocks/CU resident ========
__global__ __launch_bounds__(256, 3) void mfma_gemm_out(
    const _Float16* __restrict__ A, const _Float16* __restrict__ B,
    const float* __restrict__ bias, float* __restrict__ out) {
  __shared__ __align__(16) _Float16 As[64 * 64];
  __shared__ __align__(16) _Float16 Bs[128 * 64];
  const int K = CDIM, ntx = 12;
  const int tid = threadIdx.x;
  const int lane = tid & 63, l15 = lane & 15, quad = lane >> 4;
  const int wv = tid >> 6;
  const int wm = (wv & 1) * 32, wn = (wv >> 1) * 64;
  const int lin = blockIdx.x;
  const int cpx = gridDim.x >> 3;  // 96
  const int sw = (lin & 7) * cpx + (lin >> 3);
  const int row0 = (sw / ntx) * 64, col0 = (sw % ntx) * 128;
  f4v acc[2][4];
#pragma unroll
  for (int i = 0; i < 2; i++)
#pragma unroll
    for (int j = 0; j < 4; j++) acc[i][j] = (f4v)0.0f;

  for (int k0 = 0; k0 < K; k0 += 64) {
    __syncthreads();
#pragma unroll
    for (int p = 0; p < 2; p++) {
      int idx = tid + p * 256;
      int rr = idx >> 3, sc = idx & 7;
      int gc = (sc ^ (rr & 7)) << 3;
      gl2lds16(A + (size_t)(row0 + rr) * K + k0 + gc, As + idx * 8);
    }
#pragma unroll
    for (int p = 0; p < 4; p++) {
      int idx = tid + p * 256;
      int rr = idx >> 3, sc = idx & 7;
      int gc = (sc ^ (rr & 7)) << 3;
      gl2lds16(B + (size_t)(col0 + rr) * K + k0 + gc, Bs + idx * 8);
    }
    __syncthreads();
#pragma unroll
    for (int kc = 0; kc < 2; kc++) {
      hf8v af[2], bfr[4];
#pragma unroll
      for (int t = 0; t < 2; t++) {
        int lrA = wm + t * 16 + l15;
        af[t] = *(const hf8v*)(As + lrA * 64 + ((((kc << 2) | quad) ^ (lrA & 7)) << 3));
      }
#pragma unroll
      for (int t = 0; t < 4; t++) {
        int lrB = wn + t * 16 + l15;
        bfr[t] = *(const hf8v*)(Bs + lrB * 64 + ((((kc << 2) | quad) ^ (lrB & 7)) << 3));
      }
#pragma unroll
      for (int mt = 0; mt < 2; mt++)
#pragma unroll
        for (int nt = 0; nt < 4; nt++)
          acc[mt][nt] = mfma16(af[mt], bfr[nt], acc[mt][nt]);
    }
  }
#pragma unroll
  for (int mt = 0; mt < 2; mt++)
#pragma unroll
    for (int reg = 0; reg < 4; reg++) {
      int r = row0 + wm + mt * 16 + quad * 4 + reg;
#pragma unroll
      for (int nt = 0; nt < 4; nt++) {
        int c = col0 + wn + nt * 16 + l15;
        out[(size_t)r * HDV + c] = acc[mt][nt][reg] + bias[c];
      }
    }
}

// ================= flash MFMA attention: LDS-staged K/V/RK ==============
// Best measured config: 256 threads, 4 waves x 2 strips of 16 q-rows,
// (256,2) -> VGPR 128, 2 blocks/CU. 1-D grid with bijective XCD swizzle.
// Split-barrier iter: {issue mask,K,RK,V} -> vmcnt(6)+bar (K/RK ready, V in
// flight) -> QK/RK/softmax -> vmcnt(0)+bar (V ready) -> PV.
// NOTE (round-9 lesson): do NOT rotate staging across the PV barrier — the
// staging wait is already hidden by cross-block wave overlap (2 blocks/CU);
// rotation adds lockstep coupling and regressed 110->137 us.
// NOTE (structural): 3 blocks/CU is impossible at KVBLK=64 — K(8K)+V(24.5K)+
// RK(24.5K) = 57K irreducible > 160K/3 budget even with Pbs removed.
template <bool SPLITKV>
__global__ __launch_bounds__(256, 2) void attn_mfma(
    const _Float16* __restrict__ qb, const _Float16* __restrict__ kb,
    const _Float16* __restrict__ vtb, const _Float16* __restrict__ rkb,
    const float* __restrict__ rwb, const int* __restrict__ mask,
    _Float16* __restrict__ attn_out, float* __restrict__ Opart, float* __restrict__ ml) {
  __shared__ __align__(16) _Float16 Vts[192 * 64];   // 24576 B (pi-permuted keys)
  __shared__ __align__(16) _Float16 RKs[192 * 64];   // 24576 B
  __shared__ __align__(16) _Float16 Kts[64 * 64];    //  8192 B
  __shared__ __align__(16) _Float16 Pbs[128 * PSTR]; // 18432 B, wave-private (NOT aliased)
  // total 75776 B -> 2 blocks/CU

  const int lin = blockIdx.x;
  const int chunk = SPLITKV ? 64 : 32;            // blocks per XCD
  const int swz = (lin & 7) * chunk + (lin >> 3); // bijective: same-by -> same XCD
  const int bx = swz & 15;
  const int by = swz >> 4;
  const int i0 = bx * 128;
  const int bh = SPLITKV ? (by & 15) : by;
  const int half = SPLITKV ? (by >> 4) : 0;
  const int b = bh >> 3, h = bh & 7;
  const int tid = threadIdx.x;
  const int wv = tid >> 6, lane = tid & 63;
  const int l15 = lane & 15, quad = lane >> 4;

  // Q A-fragments, 2 strips (held in VGPRs across all key tiles)
  hf8v qf[2][2], qbf[2][2];
#pragma unroll
  for (int s = 0; s < 2; s++) {
    int qrow = i0 + wv * 32 + s * 16 + l15;
    const _Float16* qp = qb + (size_t)(b * SEQ + qrow) * HDK + h * 64;
#pragma unroll
    for (int kc = 0; kc < 2; kc++) {
      hf8v qv = *(const hf8v*)(qp + kc * 32 + quad * 8);
      qf[s][kc] = qv;
      hf8v t;
#pragma unroll
      for (int j = 0; j < 8; j++)
        t[j] = (_Float16)((float)qv[j] + rwb[h * 64 + kc * 32 + quad * 8 + j]);
      qbf[s][kc] = t;
    }
  }

  f4v Of[2][12];
#pragma unroll
  for (int s = 0; s < 2; s++)
#pragma unroll
    for (int se = 0; se < 12; se++) Of[s][se] = (f4v)0.0f;
  float m_i[2][4] = {{-INFINITY, -INFINITY, -INFINITY, -INFINITY},
                     {-INFINITY, -INFINITY, -INFINITY, -INFINITY}};
  float l_i[2][4] = {{0.f, 0.f, 0.f, 0.f}, {0.f, 0.f, 0.f, 0.f}};  // per-lane partials

  const int j0beg = SPLITKV ? half * (SEQ / 2) : 0;
  const int j0end = SPLITKV ? j0beg + SEQ / 2 : SEQ;

  for (int j0 = j0beg; j0 < j0end; j0 += 64) {
    __syncthreads();  // (a) prior-tile readers done before staging overwrites
    // mask loads FIRST: they are the oldest vmem ops, covered by the vmcnt(6) wait
    int mraw[4];
#pragma unroll
    for (int st = 0; st < 4; st++) mraw[st] = mask[b * SEQ + j0 + st * 16 + l15];
    {
      const int U0 = j0 - i0 + 1920;  // 192-row RK window base, in [0, 3904]
#pragma unroll
      for (int r = 0; r < 2; r++) {
        int idx = tid + r * 256, row = idx >> 3, sc = idx & 7;
        gl2lds16(kb + ((size_t)bh * SEQ + j0 + row) * 64 + ((sc ^ (row & 7)) << 3), Kts + idx * 8);
      }
#pragma unroll
      for (int r = 0; r < 6; r++) {
        int idx = tid + r * 256, row = idx >> 3, sc = idx & 7;
        gl2lds16(rkb + ((size_t)h * 4096 + U0 + row) * 64 + ((sc ^ (row & 7)) << 3), RKs + idx * 8);
      }
#pragma unroll
      for (int r = 0; r < 6; r++) {
        int idx = tid + r * 256, row = idx >> 3, sc = idx & 7;
        gl2lds16(vtb + ((size_t)bh * DVC + row) * SEQ + j0 + ((sc ^ (row & 7)) << 3), Vts + idx * 8);
      }
    }
    // wait for mask(4)+K(2)+RK(6) = 12 oldest; leave the 6 V loads in flight.
    // barrier-join: every wave's own K/RK are drained before its barrier, so
    // after the barrier ALL waves' K/RK writes are visible.
    asm volatile("s_waitcnt vmcnt(6)" ::: "memory");
    __builtin_amdgcn_s_barrier();
    __builtin_amdgcn_sched_barrier(0);
    float mv[4];
#pragma unroll
    for (int st = 0; st < 4; st++) mv[st] = mraw[st] ? 0.f : -1e9f;

#pragma unroll
    for (int s = 0; s < 2; s++) {
      // content logits
      __builtin_amdgcn_s_setprio(1);
      f4v Sf[4];
#pragma unroll
      for (int st = 0; st < 4; st++) {
        Sf[st] = (f4v)0.0f;
#pragma unroll
        for (int kc = 0; kc < 2; kc++) {
          int row = st * 16 + l15;
          hf8v kf = *(const hf8v*)(Kts + row * 64 + ((((kc << 2) | quad) ^ (row & 7)) << 3));
          Sf[st] = mfma16(qf[s][kc], kf, Sf[st]);
        }
      }
      // rel logits over 80-row window
      f4v Rf[5];
      const int tb = 112 - 32 * wv - 16 * s;
#pragma unroll
      for (int u = 0; u < 5; u++) {
        Rf[u] = (f4v)0.0f;
#pragma unroll
        for (int kc = 0; kc < 2; kc++) {
          int row = tb + u * 16 + l15;
          hf8v rf = *(const hf8v*)(RKs + row * 64 + ((((kc << 2) | quad) ^ (row & 7)) << 3));
          Rf[u] = mfma16(qbf[s][kc], rf, Rf[u]);
        }
      }
      __builtin_amdgcn_s_setprio(0);
      // band extraction via bpermute: S[r][c] += R[r][c-r+15]
#pragma unroll
      for (int reg = 0; reg < 4; reg++) {
        int delta = l15 - (quad << 2) - reg + 15;  // [0,30]
        int srcl = (quad << 4) | (delta & 15);
        float sh0 = __shfl(Rf[0][reg], srcl, 64);
        float sh1 = __shfl(Rf[1][reg], srcl, 64);
        float sh2 = __shfl(Rf[2][reg], srcl, 64);
        float sh3 = __shfl(Rf[3][reg], srcl, 64);
        float sh4 = __shfl(Rf[4][reg], srcl, 64);
        bool hib = delta >= 16;
        Sf[0][reg] += (hib ? sh1 : sh0) + mv[0];
        Sf[1][reg] += (hib ? sh2 : sh1) + mv[1];
        Sf[2][reg] += (hib ? sh3 : sh2) + mv[2];
        Sf[3][reg] += (hib ? sh4 : sh3) + mv[3];
      }
      // online softmax with defer-max (THR=8): row-max via DPP (VALU, not LDS);
      // rescale only when max grows by >8 -> P bounded by e^8 (fits f16).
#pragma unroll
      for (int reg = 0; reg < 4; reg++) {
        float t = fmaxf(fmaxf(Sf[0][reg], Sf[1][reg]), fmaxf(Sf[2][reg], Sf[3][reg]));
        t = rowmax16(t);
        if (__any(t - m_i[s][reg] > 8.0f)) {
          float mn = fmaxf(m_i[s][reg], t);
          float alpha = __expf(m_i[s][reg] - mn);
          m_i[s][reg] = mn;
          l_i[s][reg] *= alpha;
#pragma unroll
          for (int se = 0; se < 12; se++) Of[s][se][reg] *= alpha;
        }
        float mcur = m_i[s][reg];
        hf4v pv;
        float rs = 0.f;
#pragma unroll
        for (int st = 0; st < 4; st++) {
          float p = __expf(Sf[st][reg] - mcur);
          rs += p;
          pv[st] = (_Float16)p;
        }
        l_i[s][reg] += rs;  // per-lane partial; row-reduce in epilogue
        *(hf4v*)(Pbs + (size_t)(wv * 32 + s * 16 + quad * 4 + reg) * PSTR + l15 * 4) = pv;
      }
    }

    // PV: P A-frags (wave-private LDS, in-order DS), V B-frags from Vts (pi-ordered keys)
    hf8v pa[2][2];
#pragma unroll
    for (int s = 0; s < 2; s++)
#pragma unroll
      for (int kc = 0; kc < 2; kc++)
        pa[s][kc] = *(const hf8v*)(Pbs + (size_t)(wv * 32 + s * 16 + l15) * PSTR +
                                   kc * 32 + quad * 8);
    // drain own V loads; barrier-join makes all waves' V writes visible
    asm volatile("s_waitcnt vmcnt(0)" ::: "memory");
    __builtin_amdgcn_s_barrier();
    __builtin_amdgcn_sched_barrier(0);
    __builtin_amdgcn_s_setprio(1);
#pragma unroll
    for (int se = 0; se < 12; se++) {
#pragma unroll
      for (int kc = 0; kc < 2; kc++) {
        int row = se * 16 + l15;
        hf8v vf = *(const hf8v*)(Vts + row * 64 + ((((kc << 2) | quad) ^ (row & 7)) << 3));
        Of[0][se] = mfma16(pa[0][kc], vf, Of[0][se]);
        Of[1][se] = mfma16(pa[1][kc], vf, Of[1][se]);
      }
    }
    __builtin_amdgcn_s_setprio(0);
  }

#pragma unroll
  for (int s = 0; s < 2; s++)
#pragma unroll
    for (int reg = 0; reg < 4; reg++) {
      float ls = l_i[s][reg];
      ls += __shfl_xor(ls, 1);
      ls += __shfl_xor(ls, 2);
      ls += __shfl_xor(ls, 4);
      ls += __shfl_xor(ls, 8);
      int row = i0 + wv * 32 + s * 16 + quad * 4 + reg;
      int rg = b * SEQ + row;
      if constexpr (SPLITKV) {
        float* Op = Opart + ((size_t)(half * 4096 + rg)) * HDV + h * DVC;
#pragma unroll
        for (int se = 0; se < 12; se++) Op[se * 16 + l15] = Of[s][se][reg];
        if (l15 == 0) {
          size_t mlb = (((size_t)half * 4096 + rg) * HN + h) * 2;
          ml[mlb] = m_i[s][reg];
          ml[mlb + 1] = ls;
        }
      } else {
        float inv = 1.0f / ls;
        size_t base2 = (size_t)rg * HDV + h * DVC;
#pragma unroll
        for (int se = 0; se < 12; se++)
          attn_out[base2 + se * 16 + l15] = (_Float16)(Of[s][se][reg] * inv);
      }
    }
}

// ================= combine the two KV halves =================
__global__ __launch_bounds__(256) void combine_kernel(const float* __restrict__ Opart,
                                                      const float* __restrict__ ml,
                                                      _Float16* __restrict__ attn_out) {
  int i4 = blockIdx.x * 256 + threadIdx.x;  // over 4096*384
  int rg = i4 / 384, c4 = (i4 - rg * 384) * 4;
  int h = c4 / DVC;
  size_t mlb0 = ((size_t)rg * HN + h) * 2;
  size_t mlb1 = (((size_t)4096 + rg) * HN + h) * 2;
  float m0 = ml[mlb0], l0 = ml[mlb0 + 1];
  float m1 = ml[mlb1], l1 = ml[mlb1 + 1];
  float M = fmaxf(m0, m1);
  float w0 = __expf(m0 - M), w1 = __expf(m1 - M);
  float inv = 1.0f / (l0 * w0 + l1 * w1);
  float4 O0 = *(const float4*)(Opart + (size_t)rg * HDV + c4);
  float4 O1 = *(const float4*)(Opart + ((size_t)4096 + rg) * HDV + c4);
  _Float16 o[4] = {(_Float16)((O0.x * w0 + O1.x * w1) * inv),
                   (_Float16)((O0.y * w0 + O1.y * w1) * inv),
                   (_Float16)((O0.z * w0 + O1.z * w1) * inv),
                   (_Float16)((O0.w * w0 + O1.w * w1) * inv)};
  *(unsigned long long*)(attn_out + (size_t)rg * HDV + c4) = *(const unsigned long long*)o;
}

extern "C" void kernel_launch(void* const* d_in, const int* in_sizes, int n_in,
                              void* d_out, int out_size, void* d_ws, size_t ws_size,
                              hipStream_t stream) {
  const float* x    = (const float*)d_in[0];
  const int*   mask = (const int*)d_in[1];
  const float* Wq   = (const float*)d_in[2];
  const float* Wk   = (const float*)d_in[3];
  const float* Wv   = (const float*)d_in[4];
  const float* Wr   = (const float*)d_in[5];
  const float* rwb  = (const float*)d_in[6];
  const float* Wo   = (const float*)d_in[7];
  const float* bo   = (const float*)d_in[8];
  float* out = (float*)d_out;

  char* wsb = (char*)d_ws;
  size_t o = 0;
  auto al = [](size_t v) { return (v + 255) & ~(size_t)255; };
#define CARVE(ptr_t, name, bytes) ptr_t name = (ptr_t)(wsb + o); o = al(o + (bytes));
  CARVE(_Float16*, pe_h, (size_t)4096 * 192 * 2)
  CARVE(_Float16*, WrT, (size_t)HDK * 192 * 2)
  CARVE(_Float16*, xb, (size_t)BN * SEQ * CDIM * 2)
  CARVE(_Float16*, WTqkv, (size_t)2560 * CDIM * 2)
  CARVE(_Float16*, WoT, (size_t)HDV * CDIM * 2)
  CARVE(_Float16*, qb, (size_t)BN * SEQ * HDK * 2)
  CARVE(_Float16*, kb, (size_t)BN * SEQ * HDK * 2)
  CARVE(_Float16*, vtb, (size_t)BN * SEQ * HDV * 2)
  CARVE(_Float16*, rkb, (size_t)HN * 4096 * 64 * 2)
  _Float16* attnh = xb;  // xb dead after QKV gemm -> safe alias
  CARVE(float*, Opart, (size_t)2 * 4096 * HDV * 4)
  CARVE(float*, ml, (size_t)2 * 4096 * HN * 2 * 4)
  bool dosplit = (o <= ws_size);

  prep_kernel<<<PREP_BLOCKS, 256, 0, stream>>>(x, Wq, Wk, Wv, Wo, Wr, xb, WTqkv, WoT, WrT,
                                               pe_h);
  mfma_gemm_qkvrk<<<768, 256, 0, stream>>>(xb, WTqkv, pe_h, WrT, qb, kb, vtb, rkb);
  if (dosplit) {
    attn_mfma<true><<<512, 256, 0, stream>>>(qb, kb, vtb, rkb, rwb, mask,
                                             attnh, Opart, ml);
    combine_kernel<<<4096 * 384 / 256, 256, 0, stream>>>(Opart, ml, attnh);
  } else {
    attn_mfma<false><<<256, 256, 0, stream>>>(qb, kb, vtb, rkb, rwb, mask,
                                              attnh, nullptr, nullptr);
  }
  mfma_gemm_out<<<768, 256, 0, stream>>>(attnh, WoT, bo, out);
}

// Round 11
// 293.584 us; speedup vs baseline: 1.1413x; 1.0218x over previous
//
#include <hip/hip_runtime.h>
#include <math.h>

#define SEQ 2048
#define CDIM 1536
#define HN 8
#define DVC 192
#define BN 2
#define NPOS 4095   // 2*SEQ-1
#define HDK 512     // H*DK
#define HDV 1536    // H*DV
#define PSTR 72     // Pbs LDS stride in halfs (144 B rows: 16B-aligned, 2-way banks max)

typedef __attribute__((ext_vector_type(8))) _Float16 hf8v;  // 8 f16 (4 VGPRs)
typedef __attribute__((ext_vector_type(4))) _Float16 hf4v;  // 4 f16 (b64)
typedef __attribute__((ext_vector_type(4))) float f4v;      // 16x16 MFMA C/D frag
typedef __attribute__((ext_vector_type(16))) float f16fv;   // 32x32 MFMA C/D frag

static __device__ __forceinline__ f4v mfma16(hf8v a, hf8v b, f4v c) {
  return __builtin_amdgcn_mfma_f32_16x16x32_f16(a, b, c, 0, 0, 0);
}
static __device__ __forceinline__ f16fv mfma32(hf8v a, hf8v b, f16fv c) {
  return __builtin_amdgcn_mfma_f32_32x32x16_f16(a, b, c, 0, 0, 0);
}
static __device__ __forceinline__ void gl2lds16(const void* g, void* l) {
  __builtin_amdgcn_global_load_lds((const __attribute__((address_space(1))) unsigned int*)g,
                                   (__attribute__((address_space(3))) unsigned int*)l,
                                   16, 0, 0);
}
// 16-lane (DPP row) max butterfly via row_ror — VALU pipe, replaces 4x ds_bpermute
static __device__ __forceinline__ float rowmax16(float x) {
  x = fmaxf(x, __int_as_float(__builtin_amdgcn_update_dpp(0, __float_as_int(x), 0x128, 0xf, 0xf, true)));
  x = fmaxf(x, __int_as_float(__builtin_amdgcn_update_dpp(0, __float_as_int(x), 0x124, 0xf, 0xf, true)));
  x = fmaxf(x, __int_as_float(__builtin_amdgcn_update_dpp(0, __float_as_int(x), 0x122, 0xf, 0xf, true)));
  x = fmaxf(x, __int_as_float(__builtin_amdgcn_update_dpp(0, __float_as_int(x), 0x121, 0xf, 0xf, true)));
  return x;
}

// ============ fused prep: cast x + 5 weight transposes + pe features ============
#define CAST_B 6144
#define TWQ_B  768
#define TWK_B  768
#define TWV_B  2304
#define TWO_B  2304
#define TWR_B  96
#define PE_B   1536
#define TW_END (CAST_B + TWQ_B + TWK_B + TWV_B + TWO_B + TWR_B)
#define PREP_BLOCKS (TW_END + PE_B)

__device__ __forceinline__ void twc_tile(const float* __restrict__ W, _Float16* __restrict__ WT,
                                         int K, int N, int tile, float (*tls)[33], int tid) {
  int ntn = N >> 5;
  int nt = tile % ntn, kt = tile / ntn;
  int k0 = kt * 32, n0 = nt * 32;
  int tx = tid & 31, ty = tid >> 5;
#pragma unroll
  for (int p = 0; p < 4; p++) tls[ty + p * 8][tx] = W[(size_t)(k0 + ty + p * 8) * N + n0 + tx];
  __syncthreads();
#pragma unroll
  for (int p = 0; p < 4; p++) {
    int n = ty + p * 8;
    WT[(size_t)(n0 + n) * K + k0 + tx] = (_Float16)tls[tx][n];
  }
}

__global__ __launch_bounds__(256) void prep_kernel(
    const float* __restrict__ x, const float* __restrict__ Wq, const float* __restrict__ Wk,
    const float* __restrict__ Wv, const float* __restrict__ Wo, const float* __restrict__ Wr,
    _Float16* __restrict__ xb, _Float16* __restrict__ WTqkv, _Float16* __restrict__ WoT,
    _Float16* __restrict__ WrT, _Float16* __restrict__ pe_h) {
  __shared__ float tls[32][33];
  int blk = blockIdx.x, tid = threadIdx.x;
  if (blk < CAST_B) {
    int i = (blk * 256 + tid) * 4;
    float4 v = *(const float4*)(x + i);
    _Float16 o[4] = {(_Float16)v.x, (_Float16)v.y, (_Float16)v.z, (_Float16)v.w};
    *(unsigned long long*)(xb + i) = *(const unsigned long long*)o;
  } else if (blk < CAST_B + TWQ_B) {
    twc_tile(Wq, WTqkv + 0 * (size_t)CDIM, CDIM, HDK, blk - CAST_B, tls, tid);
  } else if (blk < CAST_B + TWQ_B + TWK_B) {
    twc_tile(Wk, WTqkv + 512 * (size_t)CDIM, CDIM, HDK, blk - (CAST_B + TWQ_B), tls, tid);
  } else if (blk < CAST_B + TWQ_B + TWK_B + TWV_B) {
    twc_tile(Wv, WTqkv + 1024 * (size_t)CDIM, CDIM, HDV, blk - (CAST_B + TWQ_B + TWK_B), tls, tid);
  } else if (blk < CAST_B + TWQ_B + TWK_B + TWV_B + TWO_B) {
    twc_tile(Wo, WoT, CDIM, HDV, blk - (CAST_B + TWQ_B + TWK_B + TWV_B), tls, tid);
  } else if (blk < TW_END) {
    twc_tile(Wr, WrT, 192, HDK, blk - (CAST_B + TWQ_B + TWK_B + TWV_B + TWO_B), tls, tid);
  } else {
    // pe features [4096][192] f16; analytic gamma max (unimodal, mode=(conc-1)/rate)
    int idx = (blk - TW_END) * 256 + tid;  // over 4096*96
    int pos = idx / 96, f = idx - pos * 96;
    float val = 0.0f, sval = 0.0f;
    if (pos < NPOS) {
      float ap = fabsf((float)(pos - (SEQ - 1)));
      int j = f & 31, cls = f >> 5;
      if (cls == 0) {
        float hl = exp2f(3.0f + 8.0f * (float)j / 31.0f);
        val = exp2f(-ap / hl);
      } else if (cls == 1) {
        float cw = exp2f((float)(j + 1)) - 1.0f;
        val = (cw > ap) ? 1.0f : 0.0f;
      } else {
        float conc = 4.0f * (float)((j + 1) * (j + 1));
        float rate = (float)(j + 1) / 16.0f;
        float log_norm = lgammaf(conc) - conc * logf(rate);
        float pv = expf((conc - 1.0f) * logf(ap) - rate * ap - log_norm) + 1e-8f;
        float mode = (conc - 1.0f) / rate;
        float a0 = fminf(floorf(mode), 2047.0f);
        float a1 = fminf(a0 + 1.0f, 2047.0f);
        float p0 = expf((conc - 1.0f) * logf(a0) - rate * a0 - log_norm) + 1e-8f;
        float p1 = expf((conc - 1.0f) * logf(a1) - rate * a1 - log_norm) + 1e-8f;
        val = pv / fmaxf(p0, p1);
      }
      float sgn = (pos > SEQ - 1) ? 1.0f : ((pos < SEQ - 1) ? -1.0f : 0.0f);
      sval = sgn * val;
    }
    pe_h[pos * 192 + f] = (_Float16)val;
    pe_h[pos * 192 + 96 + f] = (_Float16)sval;
  }
}

// ========== fused QKV + RK GEMM, 128x128xBK64, 32x32x16 MFMA ==========
// blocks [0,640): QKV — A=xb, B=WTqkv, K=1536, ntx=20; epilogue:
//   c<512 -> qb*0.125 ; c<1024 -> kb[B,H,S,64] ; else vtb[B,H,192,S] PI-PERMUTED
// blocks [640,768): RK — A=pe_h, B=WrT, K=192, ntx=4; rkb[(h*4096+pos)*64+d]
// Per-segment bijective XCD band swizzle. 32x32x16 frags: A/B row=lane&31,
// k=(lane>>5)*8+j; C/D col=lane&31, row=(reg&3)+8*(reg>>2)+4*(lane>>5)
// (HW-verified layout, m74/m101). Half the MFMA issue slots of 16x16x32.
__global__ __launch_bounds__(256, 3) void mfma_gemm_qkvrk(
    const _Float16* __restrict__ xb, const _Float16* __restrict__ WTqkv,
    const _Float16* __restrict__ pe_h, const _Float16* __restrict__ WrT,
    _Float16* __restrict__ qb, _Float16* __restrict__ kb, _Float16* __restrict__ vtb,
    _Float16* __restrict__ rkb) {
  __shared__ __align__(16) _Float16 As[128 * 64];
  __shared__ __align__(16) _Float16 Bs[128 * 64];
  const int tid = threadIdx.x;
  const int lane = tid & 63;
  const int m32 = lane & 31, hh = lane >> 5;
  const int wv = tid >> 6;
  const int wm = (wv & 1) * 64, wn = (wv >> 1) * 64;
  const bool isrk = blockIdx.x >= 640;
  const _Float16* A;
  const _Float16* B;
  int K, ntx, lin, cpx;
  if (!isrk) {
    A = xb; B = WTqkv; K = CDIM; ntx = 20; lin = blockIdx.x; cpx = 80;
  } else {
    A = pe_h; B = WrT; K = 192; ntx = 4; lin = blockIdx.x - 640; cpx = 16;
  }
  const int sw = (lin & 7) * cpx + (lin >> 3);
  const int row0 = (sw / ntx) * 128, col0 = (sw % ntx) * 128;
  f16fv acc[2][2];
#pragma unroll
  for (int i = 0; i < 2; i++)
#pragma unroll
    for (int j = 0; j < 2; j++) acc[i][j] = (f16fv)0.0f;

  for (int k0 = 0; k0 < K; k0 += 64) {
    __syncthreads();
#pragma unroll
    for (int p = 0; p < 4; p++) {
      int idx = tid + p * 256;
      int rr = idx >> 3, sc = idx & 7;
      int gc = (sc ^ (rr & 7)) << 3;
      gl2lds16(A + (size_t)(row0 + rr) * K + k0 + gc, As + idx * 8);
      gl2lds16(B + (size_t)(col0 + rr) * K + k0 + gc, Bs + idx * 8);
    }
    __syncthreads();
#pragma unroll
    for (int ks = 0; ks < 4; ks++) {  // K-chunks of 16 within BK=64
      const int kg = (ks << 1) | hh;  // 8-half group index within the 64-col row
      hf8v af[2], bf[2];
#pragma unroll
      for (int t = 0; t < 2; t++) {
        int lrA = wm + t * 32 + m32;
        int lrB = wn + t * 32 + m32;
        af[t] = *(const hf8v*)(As + lrA * 64 + ((kg ^ (lrA & 7)) << 3));
        bf[t] = *(const hf8v*)(Bs + lrB * 64 + ((kg ^ (lrB & 7)) << 3));
      }
#pragma unroll
      for (int mt = 0; mt < 2; mt++)
#pragma unroll
        for (int nt = 0; nt < 2; nt++)
          acc[mt][nt] = mfma32(af[mt], bf[nt], acc[mt][nt]);
    }
  }
#pragma unroll
  for (int mt = 0; mt < 2; mt++)
#pragma unroll
    for (int reg = 0; reg < 16; reg++) {
      int r = row0 + wm + mt * 32 + (reg & 3) + 8 * (reg >> 2) + 4 * hh;
      int bb = r >> 11, ss = r & (SEQ - 1);
#pragma unroll
      for (int nt = 0; nt < 2; nt++) {
        int c = col0 + wn + nt * 32 + m32;
        float vv = acc[mt][nt][reg];
        if (!isrk) {
          if (c < 512) {
            qb[(size_t)r * HDK + c] = (_Float16)(vv * 0.125f);
          } else if (c < 1024) {
            int cc = c - 512, h = cc >> 6, d = cc & 63;
            kb[(((size_t)bb * HN + h) * SEQ + ss) * 64 + d] = (_Float16)vv;
          } else {
            int cc = c - 1024, h = cc / DVC, e = cc - h * DVC;
            // pi-permute key within its 64-block: key k -> pos (k&15)*4 + ((k>>4)&3)
            int jp = (ss & ~63) | ((ss & 15) << 2) | ((ss >> 4) & 3);
            vtb[(((size_t)bb * HN + h) * DVC + e) * SEQ + jp] = (_Float16)vv;
          }
        } else {
          int h = c >> 6, d = c & 63;
          rkb[((size_t)h * 4096 + r) * 64 + d] = (_Float16)vv;
        }
      }
    }
}

// ======== output GEMM: 64x128xBK64, 32x32x16 MFMA, 768 blocks = 3/CU ========
__global__ __launch_bounds__(256, 3) void mfma_gemm_out(
    const _Float16* __restrict__ A, const _Float16* __restrict__ B,
    const float* __restrict__ bias, float* __restrict__ out) {
  __shared__ __align__(16) _Float16 As[64 * 64];
  __shared__ __align__(16) _Float16 Bs[128 * 64];
  const int K = CDIM, ntx = 12;
  const int tid = threadIdx.x;
  const int lane = tid & 63;
  const int m32 = lane & 31, hh = lane >> 5;
  const int wv = tid >> 6;
  const int wm = (wv & 1) * 32, wn = (wv >> 1) * 64;
  const int lin = blockIdx.x;
  const int cpx = gridDim.x >> 3;  // 96
  const int sw = (lin & 7) * cpx + (lin >> 3);
  const int row0 = (sw / ntx) * 64, col0 = (sw % ntx) * 128;
  f16fv acc[2];
#pragma unroll
  for (int j = 0; j < 2; j++) acc[j] = (f16fv)0.0f;

  for (int k0 = 0; k0 < K; k0 += 64) {
    __syncthreads();
#pragma unroll
    for (int p = 0; p < 2; p++) {
      int idx = tid + p * 256;
      int rr = idx >> 3, sc = idx & 7;
      int gc = (sc ^ (rr & 7)) << 3;
      gl2lds16(A + (size_t)(row0 + rr) * K + k0 + gc, As + idx * 8);
    }
#pragma unroll
    for (int p = 0; p < 4; p++) {
      int idx = tid + p * 256;
      int rr = idx >> 3, sc = idx & 7;
      int gc = (sc ^ (rr & 7)) << 3;
      gl2lds16(B + (size_t)(col0 + rr) * K + k0 + gc, Bs + idx * 8);
    }
    __syncthreads();
#pragma unroll
    for (int ks = 0; ks < 4; ks++) {
      const int kg = (ks << 1) | hh;
      int lrA = wm + m32;
      hf8v af = *(const hf8v*)(As + lrA * 64 + ((kg ^ (lrA & 7)) << 3));
      hf8v bf[2];
#pragma unroll
      for (int nt = 0; nt < 2; nt++) {
        int lrB = wn + nt * 32 + m32;
        bf[nt] = *(const hf8v*)(Bs + lrB * 64 + ((kg ^ (lrB & 7)) << 3));
      }
      acc[0] = mfma32(af, bf[0], acc[0]);
      acc[1] = mfma32(af, bf[1], acc[1]);
    }
  }
#pragma unroll
  for (int reg = 0; reg < 16; reg++) {
    int r = row0 + wm + (reg & 3) + 8 * (reg >> 2) + 4 * hh;
#pragma unroll
    for (int nt = 0; nt < 2; nt++) {
      int c = col0 + wn + nt * 32 + m32;
      out[(size_t)r * HDV + c] = acc[nt][reg] + bias[c];
    }
  }
}

// ================= flash MFMA attention: LDS-staged K/V/RK ==============
// Best measured config: 256 threads, 4 waves x 2 strips of 16 q-rows,
// (256,2) -> VGPR 128, 2 blocks/CU. 1-D grid with bijective XCD swizzle.
// Split-barrier iter: {issue mask,K,RK,V} -> vmcnt(6)+bar (K/RK ready, V in
// flight) -> QK/RK/softmax -> vmcnt(0)+bar (V ready) -> PV.
// NOTE (round-9 lesson): do NOT rotate staging across the PV barrier — the
// staging wait is already hidden by cross-block wave overlap (2 blocks/CU);
// rotation adds lockstep coupling and regressed 110->137 us.
// NOTE (structural): 3 blocks/CU is impossible at KVBLK=64 — K(8K)+V(24.5K)+
// RK(24.5K) = 57K irreducible > 160K/3 budget even with Pbs removed.
template <bool SPLITKV>
__global__ __launch_bounds__(256, 2) void attn_mfma(
    const _Float16* __restrict__ qb, const _Float16* __restrict__ kb,
    const _Float16* __restrict__ vtb, const _Float16* __restrict__ rkb,
    const float* __restrict__ rwb, const int* __restrict__ mask,
    _Float16* __restrict__ attn_out, float* __restrict__ Opart, float* __restrict__ ml) {
  __shared__ __align__(16) _Float16 Vts[192 * 64];   // 24576 B (pi-permuted keys)
  __shared__ __align__(16) _Float16 RKs[192 * 64];   // 24576 B
  __shared__ __align__(16) _Float16 Kts[64 * 64];    //  8192 B
  __shared__ __align__(16) _Float16 Pbs[128 * PSTR]; // 18432 B, wave-private (NOT aliased)
  // total 75776 B -> 2 blocks/CU

  const int lin = blockIdx.x;
  const int chunk = SPLITKV ? 64 : 32;            // blocks per XCD
  const int swz = (lin & 7) * chunk + (lin >> 3); // bijective: same-by -> same XCD
  const int bx = swz & 15;
  const int by = swz >> 4;
  const int i0 = bx * 128;
  const int bh = SPLITKV ? (by & 15) : by;
  const int half = SPLITKV ? (by >> 4) : 0;
  const int b = bh >> 3, h = bh & 7;
  const int tid = threadIdx.x;
  const int wv = tid >> 6, lane = tid & 63;
  const int l15 = lane & 15, quad = lane >> 4;

  // Q A-fragments, 2 strips (held in VGPRs across all key tiles)
  hf8v qf[2][2], qbf[2][2];
#pragma unroll
  for (int s = 0; s < 2; s++) {
    int qrow = i0 + wv * 32 + s * 16 + l15;
    const _Float16* qp = qb + (size_t)(b * SEQ + qrow) * HDK + h * 64;
#pragma unroll
    for (int kc = 0; kc < 2; kc++) {
      hf8v qv = *(const hf8v*)(qp + kc * 32 + quad * 8);
      qf[s][kc] = qv;
      hf8v t;
#pragma unroll
      for (int j = 0; j < 8; j++)
        t[j] = (_Float16)((float)qv[j] + rwb[h * 64 + kc * 32 + quad * 8 + j]);
      qbf[s][kc] = t;
    }
  }

  f4v Of[2][12];
#pragma unroll
  for (int s = 0; s < 2; s++)
#pragma unroll
    for (int se = 0; se < 12; se++) Of[s][se] = (f4v)0.0f;
  float m_i[2][4] = {{-INFINITY, -INFINITY, -INFINITY, -INFINITY},
                     {-INFINITY, -INFINITY, -INFINITY, -INFINITY}};
  float l_i[2][4] = {{0.f, 0.f, 0.f, 0.f}, {0.f, 0.f, 0.f, 0.f}};  // per-lane partials

  const int j0beg = SPLITKV ? half * (SEQ / 2) : 0;
  const int j0end = SPLITKV ? j0beg + SEQ / 2 : SEQ;

  for (int j0 = j0beg; j0 < j0end; j0 += 64) {
    __syncthreads();  // (a) prior-tile readers done before staging overwrites
    // mask loads FIRST: they are the oldest vmem ops, covered by the vmcnt(6) wait
    int mraw[4];
#pragma unroll
    for (int st = 0; st < 4; st++) mraw[st] = mask[b * SEQ + j0 + st * 16 + l15];
    {
      const int U0 = j0 - i0 + 1920;  // 192-row RK window base, in [0, 3904]
#pragma unroll
      for (int r = 0; r < 2; r++) {
        int idx = tid + r * 256, row = idx >> 3, sc = idx & 7;
        gl2lds16(kb + ((size_t)bh * SEQ + j0 + row) * 64 + ((sc ^ (row & 7)) << 3), Kts + idx * 8);
      }
#pragma unroll
      for (int r = 0; r < 6; r++) {
        int idx = tid + r * 256, row = idx >> 3, sc = idx & 7;
        gl2lds16(rkb + ((size_t)h * 4096 + U0 + row) * 64 + ((sc ^ (row & 7)) << 3), RKs + idx * 8);
      }
#pragma unroll
      for (int r = 0; r < 6; r++) {
        int idx = tid + r * 256, row = idx >> 3, sc = idx & 7;
        gl2lds16(vtb + ((size_t)bh * DVC + row) * SEQ + j0 + ((sc ^ (row & 7)) << 3), Vts + idx * 8);
      }
    }
    // wait for mask(4)+K(2)+RK(6) = 12 oldest; leave the 6 V loads in flight.
    // barrier-join: every wave's own K/RK are drained before its barrier, so
    // after the barrier ALL waves' K/RK writes are visible.
    asm volatile("s_waitcnt vmcnt(6)" ::: "memory");
    __builtin_amdgcn_s_barrier();
    __builtin_amdgcn_sched_barrier(0);
    float mv[4];
#pragma unroll
    for (int st = 0; st < 4; st++) mv[st] = mraw[st] ? 0.f : -1e9f;

#pragma unroll
    for (int s = 0; s < 2; s++) {
      // content logits
      __builtin_amdgcn_s_setprio(1);
      f4v Sf[4];
#pragma unroll
      for (int st = 0; st < 4; st++) {
        Sf[st] = (f4v)0.0f;
#pragma unroll
        for (int kc = 0; kc < 2; kc++) {
          int row = st * 16 + l15;
          hf8v kf = *(const hf8v*)(Kts + row * 64 + ((((kc << 2) | quad) ^ (row & 7)) << 3));
          Sf[st] = mfma16(qf[s][kc], kf, Sf[st]);
        }
      }
      // rel logits over 80-row window
      f4v Rf[5];
      const int tb = 112 - 32 * wv - 16 * s;
#pragma unroll
      for (int u = 0; u < 5; u++) {
        Rf[u] = (f4v)0.0f;
#pragma unroll
        for (int kc = 0; kc < 2; kc++) {
          int row = tb + u * 16 + l15;
          hf8v rf = *(const hf8v*)(RKs + row * 64 + ((((kc << 2) | quad) ^ (row & 7)) << 3));
          Rf[u] = mfma16(qbf[s][kc], rf, Rf[u]);
        }
      }
      __builtin_amdgcn_s_setprio(0);
      // band extraction via bpermute: S[r][c] += R[r][c-r+15]
#pragma unroll
      for (int reg = 0; reg < 4; reg++) {
        int delta = l15 - (quad << 2) - reg + 15;  // [0,30]
        int srcl = (quad << 4) | (delta & 15);
        float sh0 = __shfl(Rf[0][reg], srcl, 64);
        float sh1 = __shfl(Rf[1][reg], srcl, 64);
        float sh2 = __shfl(Rf[2][reg], srcl, 64);
        float sh3 = __shfl(Rf[3][reg], srcl, 64);
        float sh4 = __shfl(Rf[4][reg], srcl, 64);
        bool hib = delta >= 16;
        Sf[0][reg] += (hib ? sh1 : sh0) + mv[0];
        Sf[1][reg] += (hib ? sh2 : sh1) + mv[1];
        Sf[2][reg] += (hib ? sh3 : sh2) + mv[2];
        Sf[3][reg] += (hib ? sh4 : sh3) + mv[3];
      }
      // online softmax with defer-max (THR=8): row-max via DPP (VALU, not LDS);
      // rescale only when max grows by >8 -> P bounded by e^8 (fits f16).
#pragma unroll
      for (int reg = 0; reg < 4; reg++) {
        float t = fmaxf(fmaxf(Sf[0][reg], Sf[1][reg]), fmaxf(Sf[2][reg], Sf[3][reg]));
        t = rowmax16(t);
        if (__any(t - m_i[s][reg] > 8.0f)) {
          float mn = fmaxf(m_i[s][reg], t);
          float alpha = __expf(m_i[s][reg] - mn);
          m_i[s][reg] = mn;
          l_i[s][reg] *= alpha;
#pragma unroll
          for (int se = 0; se < 12; se++) Of[s][se][reg] *= alpha;
        }
        float mcur = m_i[s][reg];
        hf4v pv;
        float rs = 0.f;
#pragma unroll
        for (int st = 0; st < 4; st++) {
          float p = __expf(Sf[st][reg] - mcur);
          rs += p;
          pv[st] = (_Float16)p;
        }
        l_i[s][reg] += rs;  // per-lane partial; row-reduce in epilogue
        *(hf4v*)(Pbs + (size_t)(wv * 32 + s * 16 + quad * 4 + reg) * PSTR + l15 * 4) = pv;
      }
    }

    // PV: P A-frags (wave-private LDS, in-order DS), V B-frags from Vts (pi-ordered keys)
    hf8v pa[2][2];
#pragma unroll
    for (int s = 0; s < 2; s++)
#pragma unroll
      for (int kc = 0; kc < 2; kc++)
        pa[s][kc] = *(const hf8v*)(Pbs + (size_t)(wv * 32 + s * 16 + l15) * PSTR +
                                   kc * 32 + quad * 8);
    // drain own V loads; barrier-join makes all waves' V writes visible
    asm volatile("s_waitcnt vmcnt(0)" ::: "memory");
    __builtin_amdgcn_s_barrier();
    __builtin_amdgcn_sched_barrier(0);
    __builtin_amdgcn_s_setprio(1);
#pragma unroll
    for (int se = 0; se < 12; se++) {
#pragma unroll
      for (int kc = 0; kc < 2; kc++) {
        int row = se * 16 + l15;
        hf8v vf = *(const hf8v*)(Vts + row * 64 + ((((kc << 2) | quad) ^ (row & 7)) << 3));
        Of[0][se] = mfma16(pa[0][kc], vf, Of[0][se]);
        Of[1][se] = mfma16(pa[1][kc], vf, Of[1][se]);
      }
    }
    __builtin_amdgcn_s_setprio(0);
  }

#pragma unroll
  for (int s = 0; s < 2; s++)
#pragma unroll
    for (int reg = 0; reg < 4; reg++) {
      float ls = l_i[s][reg];
      ls += __shfl_xor(ls, 1);
      ls += __shfl_xor(ls, 2);
      ls += __shfl_xor(ls, 4);
      ls += __shfl_xor(ls, 8);
      int row = i0 + wv * 32 + s * 16 + quad * 4 + reg;
      int rg = b * SEQ + row;
      if constexpr (SPLITKV) {
        float* Op = Opart + ((size_t)(half * 4096 + rg)) * HDV + h * DVC;
#pragma unroll
        for (int se = 0; se < 12; se++) Op[se * 16 + l15] = Of[s][se][reg];
        if (l15 == 0) {
          size_t mlb = (((size_t)half * 4096 + rg) * HN + h) * 2;
          ml[mlb] = m_i[s][reg];
          ml[mlb + 1] = ls;
        }
      } else {
        float inv = 1.0f / ls;
        size_t base2 = (size_t)rg * HDV + h * DVC;
#pragma unroll
        for (int se = 0; se < 12; se++)
          attn_out[base2 + se * 16 + l15] = (_Float16)(Of[s][se][reg] * inv);
      }
    }
}

// ================= combine the two KV halves =================
__global__ __launch_bounds__(256) void combine_kernel(const float* __restrict__ Opart,
                                                      const float* __restrict__ ml,
                                                      _Float16* __restrict__ attn_out) {
  int i4 = blockIdx.x * 256 + threadIdx.x;  // over 4096*384
  int rg = i4 / 384, c4 = (i4 - rg * 384) * 4;
  int h = c4 / DVC;
  size_t mlb0 = ((size_t)rg * HN + h) * 2;
  size_t mlb1 = (((size_t)4096 + rg) * HN + h) * 2;
  float m0 = ml[mlb0], l0 = ml[mlb0 + 1];
  float m1 = ml[mlb1], l1 = ml[mlb1 + 1];
  float M = fmaxf(m0, m1);
  float w0 = __expf(m0 - M), w1 = __expf(m1 - M);
  float inv = 1.0f / (l0 * w0 + l1 * w1);
  float4 O0 = *(const float4*)(Opart + (size_t)rg * HDV + c4);
  float4 O1 = *(const float4*)(Opart + ((size_t)4096 + rg) * HDV + c4);
  _Float16 o[4] = {(_Float16)((O0.x * w0 + O1.x * w1) * inv),
                   (_Float16)((O0.y * w0 + O1.y * w1) * inv),
                   (_Float16)((O0.z * w0 + O1.z * w1) * inv),
                   (_Float16)((O0.w * w0 + O1.w * w1) * inv)};
  *(unsigned long long*)(attn_out + (size_t)rg * HDV + c4) = *(const unsigned long long*)o;
}

extern "C" void kernel_launch(void* const* d_in, const int* in_sizes, int n_in,
                              void* d_out, int out_size, void* d_ws, size_t ws_size,
                              hipStream_t stream) {
  const float* x    = (const float*)d_in[0];
  const int*   mask = (const int*)d_in[1];
  const float* Wq   = (const float*)d_in[2];
  const float* Wk   = (const float*)d_in[3];
  const float* Wv   = (const float*)d_in[4];
  const float* Wr   = (const float*)d_in[5];
  const float* rwb  = (const float*)d_in[6];
  const float* Wo   = (const float*)d_in[7];
  const float* bo   = (const float*)d_in[8];
  float* out = (float*)d_out;

  char* wsb = (char*)d_ws;
  size_t o = 0;
  auto al = [](size_t v) { return (v + 255) & ~(size_t)255; };
#define CARVE(ptr_t, name, bytes) ptr_t name = (ptr_t)(wsb + o); o = al(o + (bytes));
  CARVE(_Float16*, pe_h, (size_t)4096 * 192 * 2)
  CARVE(_Float16*, WrT, (size_t)HDK * 192 * 2)
  CARVE(_Float16*, xb, (size_t)BN * SEQ * CDIM * 2)
  CARVE(_Float16*, WTqkv, (size_t)2560 * CDIM * 2)
  CARVE(_Float16*, WoT, (size_t)HDV * CDIM * 2)
  CARVE(_Float16*, qb, (size_t)BN * SEQ * HDK * 2)
  CARVE(_Float16*, kb, (size_t)BN * SEQ * HDK * 2)
  CARVE(_Float16*, vtb, (size_t)BN * SEQ * HDV * 2)
  CARVE(_Float16*, rkb, (size_t)HN * 4096 * 64 * 2)
  _Float16* attnh = xb;  // xb dead after QKV gemm -> safe alias
  CARVE(float*, Opart, (size_t)2 * 4096 * HDV * 4)
  CARVE(float*, ml, (size_t)2 * 4096 * HN * 2 * 4)
  bool dosplit = (o <= ws_size);

  prep_kernel<<<PREP_BLOCKS, 256, 0, stream>>>(x, Wq, Wk, Wv, Wo, Wr, xb, WTqkv, WoT, WrT,
                                               pe_h);
  mfma_gemm_qkvrk<<<768, 256, 0, stream>>>(xb, WTqkv, pe_h, WrT, qb, kb, vtb, rkb);
  if (dosplit) {
    attn_mfma<true><<<512, 256, 0, stream>>>(qb, kb, vtb, rkb, rwb, mask,
                                             attnh, Opart, ml);
    combine_kernel<<<4096 * 384 / 256, 256, 0, stream>>>(Opart, ml, attnh);
  } else {
    attn_mfma<false><<<256, 256, 0, stream>>>(qb, kb, vtb, rkb, rwb, mask,
                                              attnh, nullptr, nullptr);
  }
  mfma_gemm_out<<<768, 256, 0, stream>>>(attnh, WoT, bo, out);
}

// Round 12
// 275.406 us; speedup vs baseline: 1.2167x; 1.0660x over previous
//
#include <hip/hip_runtime.h>
#include <math.h>

#define SEQ 2048
#define CDIM 1536
#define HN 8
#define DVC 192
#define BN 2
#define NPOS 4095   // 2*SEQ-1
#define HDK 512     // H*DK
#define HDV 1536    // H*DV
#define PSTR 72     // Pbs LDS stride in halfs (144 B rows: 16B-aligned, 2-way banks max)

typedef __attribute__((ext_vector_type(8))) _Float16 hf8v;  // 8 f16 (4 VGPRs)
typedef __attribute__((ext_vector_type(4))) _Float16 hf4v;  // 4 f16 (b64)
typedef __attribute__((ext_vector_type(4))) float f4v;      // 16x16 MFMA C/D frag
typedef __attribute__((ext_vector_type(16))) float f16fv;   // 32x32 MFMA C/D frag

static __device__ __forceinline__ f4v mfma16(hf8v a, hf8v b, f4v c) {
  return __builtin_amdgcn_mfma_f32_16x16x32_f16(a, b, c, 0, 0, 0);
}
static __device__ __forceinline__ f16fv mfma32(hf8v a, hf8v b, f16fv c) {
  return __builtin_amdgcn_mfma_f32_32x32x16_f16(a, b, c, 0, 0, 0);
}
static __device__ __forceinline__ void gl2lds16(const void* g, void* l) {
  __builtin_amdgcn_global_load_lds((const __attribute__((address_space(1))) unsigned int*)g,
                                   (__attribute__((address_space(3))) unsigned int*)l,
                                   16, 0, 0);
}
// 16-lane (DPP row) max butterfly via row_ror — VALU pipe, replaces 4x ds_bpermute
static __device__ __forceinline__ float rowmax16(float x) {
  x = fmaxf(x, __int_as_float(__builtin_amdgcn_update_dpp(0, __float_as_int(x), 0x128, 0xf, 0xf, true)));
  x = fmaxf(x, __int_as_float(__builtin_amdgcn_update_dpp(0, __float_as_int(x), 0x124, 0xf, 0xf, true)));
  x = fmaxf(x, __int_as_float(__builtin_amdgcn_update_dpp(0, __float_as_int(x), 0x122, 0xf, 0xf, true)));
  x = fmaxf(x, __int_as_float(__builtin_amdgcn_update_dpp(0, __float_as_int(x), 0x121, 0xf, 0xf, true)));
  return x;
}

// ============ fused prep: cast x + 5 weight transposes + pe features ============
#define CAST_B 6144
#define TWQ_B  768
#define TWK_B  768
#define TWV_B  2304
#define TWO_B  2304
#define TWR_B  96
#define PE_B   1536
#define TW_END (CAST_B + TWQ_B + TWK_B + TWV_B + TWO_B + TWR_B)
#define PREP_BLOCKS (TW_END + PE_B)

__device__ __forceinline__ void twc_tile(const float* __restrict__ W, _Float16* __restrict__ WT,
                                         int K, int N, int tile, float (*tls)[33], int tid) {
  int ntn = N >> 5;
  int nt = tile % ntn, kt = tile / ntn;
  int k0 = kt * 32, n0 = nt * 32;
  int tx = tid & 31, ty = tid >> 5;
#pragma unroll
  for (int p = 0; p < 4; p++) tls[ty + p * 8][tx] = W[(size_t)(k0 + ty + p * 8) * N + n0 + tx];
  __syncthreads();
#pragma unroll
  for (int p = 0; p < 4; p++) {
    int n = ty + p * 8;
    WT[(size_t)(n0 + n) * K + k0 + tx] = (_Float16)tls[tx][n];
  }
}

__global__ __launch_bounds__(256) void prep_kernel(
    const float* __restrict__ x, const float* __restrict__ Wq, const float* __restrict__ Wk,
    const float* __restrict__ Wv, const float* __restrict__ Wo, const float* __restrict__ Wr,
    _Float16* __restrict__ xb, _Float16* __restrict__ WTqkv, _Float16* __restrict__ WoT,
    _Float16* __restrict__ WrT, _Float16* __restrict__ pe_h) {
  __shared__ float tls[32][33];
  int blk = blockIdx.x, tid = threadIdx.x;
  if (blk < CAST_B) {
    int i = (blk * 256 + tid) * 4;
    float4 v = *(const float4*)(x + i);
    _Float16 o[4] = {(_Float16)v.x, (_Float16)v.y, (_Float16)v.z, (_Float16)v.w};
    *(unsigned long long*)(xb + i) = *(const unsigned long long*)o;
  } else if (blk < CAST_B + TWQ_B) {
    twc_tile(Wq, WTqkv + 0 * (size_t)CDIM, CDIM, HDK, blk - CAST_B, tls, tid);
  } else if (blk < CAST_B + TWQ_B + TWK_B) {
    twc_tile(Wk, WTqkv + 512 * (size_t)CDIM, CDIM, HDK, blk - (CAST_B + TWQ_B), tls, tid);
  } else if (blk < CAST_B + TWQ_B + TWK_B + TWV_B) {
    twc_tile(Wv, WTqkv + 1024 * (size_t)CDIM, CDIM, HDV, blk - (CAST_B + TWQ_B + TWK_B), tls, tid);
  } else if (blk < CAST_B + TWQ_B + TWK_B + TWV_B + TWO_B) {
    twc_tile(Wo, WoT, CDIM, HDV, blk - (CAST_B + TWQ_B + TWK_B + TWV_B), tls, tid);
  } else if (blk < TW_END) {
    twc_tile(Wr, WrT, 192, HDK, blk - (CAST_B + TWQ_B + TWK_B + TWV_B + TWO_B), tls, tid);
  } else {
    // pe features [4096][192] f16; analytic gamma max (unimodal, mode=(conc-1)/rate)
    int idx = (blk - TW_END) * 256 + tid;  // over 4096*96
    int pos = idx / 96, f = idx - pos * 96;
    float val = 0.0f, sval = 0.0f;
    if (pos < NPOS) {
      float ap = fabsf((float)(pos - (SEQ - 1)));
      int j = f & 31, cls = f >> 5;
      if (cls == 0) {
        float hl = exp2f(3.0f + 8.0f * (float)j / 31.0f);
        val = exp2f(-ap / hl);
      } else if (cls == 1) {
        float cw = exp2f((float)(j + 1)) - 1.0f;
        val = (cw > ap) ? 1.0f : 0.0f;
      } else {
        float conc = 4.0f * (float)((j + 1) * (j + 1));
        float rate = (float)(j + 1) / 16.0f;
        float log_norm = lgammaf(conc) - conc * logf(rate);
        float pv = expf((conc - 1.0f) * logf(ap) - rate * ap - log_norm) + 1e-8f;
        float mode = (conc - 1.0f) / rate;
        float a0 = fminf(floorf(mode), 2047.0f);
        float a1 = fminf(a0 + 1.0f, 2047.0f);
        float p0 = expf((conc - 1.0f) * logf(a0) - rate * a0 - log_norm) + 1e-8f;
        float p1 = expf((conc - 1.0f) * logf(a1) - rate * a1 - log_norm) + 1e-8f;
        val = pv / fmaxf(p0, p1);
      }
      float sgn = (pos > SEQ - 1) ? 1.0f : ((pos < SEQ - 1) ? -1.0f : 0.0f);
      sval = sgn * val;
    }
    pe_h[pos * 192 + f] = (_Float16)val;
    pe_h[pos * 192 + 96 + f] = (_Float16)sval;
  }
}

// ========== fused QKV + RK GEMM, 128x128xBK64, 32x32x16 MFMA ==========
// blocks [0,640): QKV — A=xb, B=WTqkv, K=1536, ntx=20; epilogue:
//   c<512 -> qb*0.125 ; c<1024 -> kb[B,H,S,64] ; else vtb[B,H,192,S] PI-PERMUTED
// blocks [640,768): RK — A=pe_h, B=WrT, K=192, ntx=4; rkb[(h*4096+pos)*64+d]
// Per-segment bijective XCD band swizzle. 32x32x16 frags: A/B row=lane&31,
// k=(lane>>5)*8+j; C/D col=lane&31, row=(reg&3)+8*(reg>>2)+4*(lane>>5)
// (HW-verified layout, m74/m101). Half the MFMA issue slots of 16x16x32.
__global__ __launch_bounds__(256, 3) void mfma_gemm_qkvrk(
    const _Float16* __restrict__ xb, const _Float16* __restrict__ WTqkv,
    const _Float16* __restrict__ pe_h, const _Float16* __restrict__ WrT,
    _Float16* __restrict__ qb, _Float16* __restrict__ kb, _Float16* __restrict__ vtb,
    _Float16* __restrict__ rkb) {
  __shared__ __align__(16) _Float16 As[128 * 64];
  __shared__ __align__(16) _Float16 Bs[128 * 64];
  const int tid = threadIdx.x;
  const int lane = tid & 63;
  const int m32 = lane & 31, hh = lane >> 5;
  const int wv = tid >> 6;
  const int wm = (wv & 1) * 64, wn = (wv >> 1) * 64;
  const bool isrk = blockIdx.x >= 640;
  const _Float16* A;
  const _Float16* B;
  int K, ntx, lin, cpx;
  if (!isrk) {
    A = xb; B = WTqkv; K = CDIM; ntx = 20; lin = blockIdx.x; cpx = 80;
  } else {
    A = pe_h; B = WrT; K = 192; ntx = 4; lin = blockIdx.x - 640; cpx = 16;
  }
  const int sw = (lin & 7) * cpx + (lin >> 3);
  const int row0 = (sw / ntx) * 128, col0 = (sw % ntx) * 128;
  f16fv acc[2][2];
#pragma unroll
  for (int i = 0; i < 2; i++)
#pragma unroll
    for (int j = 0; j < 2; j++) acc[i][j] = (f16fv)0.0f;

  for (int k0 = 0; k0 < K; k0 += 64) {
    __syncthreads();
#pragma unroll
    for (int p = 0; p < 4; p++) {
      int idx = tid + p * 256;
      int rr = idx >> 3, sc = idx & 7;
      int gc = (sc ^ (rr & 7)) << 3;
      gl2lds16(A + (size_t)(row0 + rr) * K + k0 + gc, As + idx * 8);
      gl2lds16(B + (size_t)(col0 + rr) * K + k0 + gc, Bs + idx * 8);
    }
    __syncthreads();
#pragma unroll
    for (int ks = 0; ks < 4; ks++) {  // K-chunks of 16 within BK=64
      const int kg = (ks << 1) | hh;  // 8-half group index within the 64-col row
      hf8v af[2], bf[2];
#pragma unroll
      for (int t = 0; t < 2; t++) {
        int lrA = wm + t * 32 + m32;
        int lrB = wn + t * 32 + m32;
        af[t] = *(const hf8v*)(As + lrA * 64 + ((kg ^ (lrA & 7)) << 3));
        bf[t] = *(const hf8v*)(Bs + lrB * 64 + ((kg ^ (lrB & 7)) << 3));
      }
#pragma unroll
      for (int mt = 0; mt < 2; mt++)
#pragma unroll
        for (int nt = 0; nt < 2; nt++)
          acc[mt][nt] = mfma32(af[mt], bf[nt], acc[mt][nt]);
    }
  }
#pragma unroll
  for (int mt = 0; mt < 2; mt++)
#pragma unroll
    for (int reg = 0; reg < 16; reg++) {
      int r = row0 + wm + mt * 32 + (reg & 3) + 8 * (reg >> 2) + 4 * hh;
      int bb = r >> 11, ss = r & (SEQ - 1);
#pragma unroll
      for (int nt = 0; nt < 2; nt++) {
        int c = col0 + wn + nt * 32 + m32;
        float vv = acc[mt][nt][reg];
        if (!isrk) {
          if (c < 512) {
            qb[(size_t)r * HDK + c] = (_Float16)(vv * 0.125f);
          } else if (c < 1024) {
            int cc = c - 512, h = cc >> 6, d = cc & 63;
            kb[(((size_t)bb * HN + h) * SEQ + ss) * 64 + d] = (_Float16)vv;
          } else {
            int cc = c - 1024, h = cc / DVC, e = cc - h * DVC;
            // pi-permute key within its 64-block: key k -> pos (k&15)*4 + ((k>>4)&3)
            int jp = (ss & ~63) | ((ss & 15) << 2) | ((ss >> 4) & 3);
            vtb[(((size_t)bb * HN + h) * DVC + e) * SEQ + jp] = (_Float16)vv;
          }
        } else {
          int h = c >> 6, d = c & 63;
          rkb[((size_t)h * 4096 + r) * 64 + d] = (_Float16)vv;
        }
      }
    }
}

// ======== output GEMM: 64x128xBK64, 32x32x16 MFMA, 768 blocks = 3/CU ========
__global__ __launch_bounds__(256, 3) void mfma_gemm_out(
    const _Float16* __restrict__ A, const _Float16* __restrict__ B,
    const float* __restrict__ bias, float* __restrict__ out) {
  __shared__ __align__(16) _Float16 As[64 * 64];
  __shared__ __align__(16) _Float16 Bs[128 * 64];
  const int K = CDIM, ntx = 12;
  const int tid = threadIdx.x;
  const int lane = tid & 63;
  const int m32 = lane & 31, hh = lane >> 5;
  const int wv = tid >> 6;
  const int wm = (wv & 1) * 32, wn = (wv >> 1) * 64;
  const int lin = blockIdx.x;
  const int cpx = gridDim.x >> 3;  // 96
  const int sw = (lin & 7) * cpx + (lin >> 3);
  const int row0 = (sw / ntx) * 64, col0 = (sw % ntx) * 128;
  f16fv acc[2];
#pragma unroll
  for (int j = 0; j < 2; j++) acc[j] = (f16fv)0.0f;

  for (int k0 = 0; k0 < K; k0 += 64) {
    __syncthreads();
#pragma unroll
    for (int p = 0; p < 2; p++) {
      int idx = tid + p * 256;
      int rr = idx >> 3, sc = idx & 7;
      int gc = (sc ^ (rr & 7)) << 3;
      gl2lds16(A + (size_t)(row0 + rr) * K + k0 + gc, As + idx * 8);
    }
#pragma unroll
    for (int p = 0; p < 4; p++) {
      int idx = tid + p * 256;
      int rr = idx >> 3, sc = idx & 7;
      int gc = (sc ^ (rr & 7)) << 3;
      gl2lds16(B + (size_t)(col0 + rr) * K + k0 + gc, Bs + idx * 8);
    }
    __syncthreads();
#pragma unroll
    for (int ks = 0; ks < 4; ks++) {
      const int kg = (ks << 1) | hh;
      int lrA = wm + m32;
      hf8v af = *(const hf8v*)(As + lrA * 64 + ((kg ^ (lrA & 7)) << 3));
      hf8v bf[2];
#pragma unroll
      for (int nt = 0; nt < 2; nt++) {
        int lrB = wn + nt * 32 + m32;
        bf[nt] = *(const hf8v*)(Bs + lrB * 64 + ((kg ^ (lrB & 7)) << 3));
      }
      acc[0] = mfma32(af, bf[0], acc[0]);
      acc[1] = mfma32(af, bf[1], acc[1]);
    }
  }
#pragma unroll
  for (int reg = 0; reg < 16; reg++) {
    int r = row0 + wm + (reg & 3) + 8 * (reg >> 2) + 4 * hh;
#pragma unroll
    for (int nt = 0; nt < 2; nt++) {
      int c = col0 + wn + nt * 32 + m32;
      out[(size_t)r * HDV + c] = acc[nt][reg] + bias[c];
    }
  }
}

// ================= flash MFMA attention: LDS-staged K/V/RK ==============
// Best measured config: 256 threads, 4 waves x 2 strips of 16 q-rows,
// (256,2) -> VGPR 128, 2 blocks/CU. 1-D grid with bijective XCD swizzle.
// Split-barrier iter: {issue mask,K,RK,V} -> vmcnt(6)+bar (K/RK ready, V in
// flight) -> QK/RK/softmax -> vmcnt(0)+bar (V ready) -> PV.
// RK is a ROLLING mod-192 circular buffer: window advances 64 rows/tile, so
// steady-state stages only the 64 NEW rows (2 gl2lds vs 6). Wrap boundaries
// (64/128) are 8-row aligned => never split a wave's gl2lds group (preserves
// the wave-uniform-base + lane*16B constraint); phys&7 == windowrow&7 (bases
// are multiples of 64) => XOR swizzle unchanged on both sides. vmcnt(6)
// covers both first-iter-full (12 older) and steady (8 older) cases.
// NOTE (round-9 lesson): do NOT rotate staging across the PV barrier.
// NOTE (structural): 3 blocks/CU impossible at KVBLK=64 (57K irreducible LDS).
template <bool SPLITKV>
__global__ __launch_bounds__(256, 2) void attn_mfma(
    const _Float16* __restrict__ qb, const _Float16* __restrict__ kb,
    const _Float16* __restrict__ vtb, const _Float16* __restrict__ rkb,
    const float* __restrict__ rwb, const int* __restrict__ mask,
    _Float16* __restrict__ attn_out, float* __restrict__ Opart, float* __restrict__ ml) {
  __shared__ __align__(16) _Float16 Vts[192 * 64];   // 24576 B (pi-permuted keys)
  __shared__ __align__(16) _Float16 RKs[192 * 64];   // 24576 B (rolling mod-192)
  __shared__ __align__(16) _Float16 Kts[64 * 64];    //  8192 B
  __shared__ __align__(16) _Float16 Pbs[128 * PSTR]; // 18432 B, wave-private (NOT aliased)
  // total 75776 B -> 2 blocks/CU

  const int lin = blockIdx.x;
  const int chunk = SPLITKV ? 64 : 32;            // blocks per XCD
  const int swz = (lin & 7) * chunk + (lin >> 3); // bijective: same-by -> same XCD
  const int bx = swz & 15;
  const int by = swz >> 4;
  const int i0 = bx * 128;
  const int bh = SPLITKV ? (by & 15) : by;
  const int half = SPLITKV ? (by >> 4) : 0;
  const int b = bh >> 3, h = bh & 7;
  const int tid = threadIdx.x;
  const int wv = tid >> 6, lane = tid & 63;
  const int l15 = lane & 15, quad = lane >> 4;

  // Q A-fragments, 2 strips (held in VGPRs across all key tiles)
  hf8v qf[2][2], qbf[2][2];
#pragma unroll
  for (int s = 0; s < 2; s++) {
    int qrow = i0 + wv * 32 + s * 16 + l15;
    const _Float16* qp = qb + (size_t)(b * SEQ + qrow) * HDK + h * 64;
#pragma unroll
    for (int kc = 0; kc < 2; kc++) {
      hf8v qv = *(const hf8v*)(qp + kc * 32 + quad * 8);
      qf[s][kc] = qv;
      hf8v t;
#pragma unroll
      for (int j = 0; j < 8; j++)
        t[j] = (_Float16)((float)qv[j] + rwb[h * 64 + kc * 32 + quad * 8 + j]);
      qbf[s][kc] = t;
    }
  }

  f4v Of[2][12];
#pragma unroll
  for (int s = 0; s < 2; s++)
#pragma unroll
    for (int se = 0; se < 12; se++) Of[s][se] = (f4v)0.0f;
  float m_i[2][4] = {{-INFINITY, -INFINITY, -INFINITY, -INFINITY},
                     {-INFINITY, -INFINITY, -INFINITY, -INFINITY}};
  float l_i[2][4] = {{0.f, 0.f, 0.f, 0.f}, {0.f, 0.f, 0.f, 0.f}};  // per-lane partials

  const int j0beg = SPLITKV ? half * (SEQ / 2) : 0;
  const int j0end = SPLITKV ? j0beg + SEQ / 2 : SEQ;

  int u0m = (j0beg - i0 + 1920) % 192;  // phys base of RK window (mod 192)

  for (int j0 = j0beg; j0 < j0end; j0 += 64) {
    __syncthreads();  // (a) prior-tile readers done before staging overwrites
    // mask loads FIRST: oldest vmem ops, covered by the vmcnt(6) wait
    int mraw[4];
#pragma unroll
    for (int st = 0; st < 4; st++) mraw[st] = mask[b * SEQ + j0 + st * 16 + l15];
    {
      const int U0 = j0 - i0 + 1920;  // 192-row RK window base, in [0, 3904]
#pragma unroll
      for (int r = 0; r < 2; r++) {
        int idx = tid + r * 256, row = idx >> 3, sc = idx & 7;
        gl2lds16(kb + ((size_t)bh * SEQ + j0 + row) * 64 + ((sc ^ (row & 7)) << 3), Kts + idx * 8);
      }
      if (j0 == j0beg) {
        // first tile: stage full 192-row window into phys (row+u0m)%192
#pragma unroll
        for (int r = 0; r < 6; r++) {
          int idx = tid + r * 256, row = idx >> 3, sc = idx & 7;
          int ph = row + u0m;
          if (ph >= 192) ph -= 192;
          gl2lds16(rkb + ((size_t)h * 4096 + U0 + row) * 64 + ((sc ^ (row & 7)) << 3),
                   RKs + ph * 64 + sc * 8);
        }
      } else {
        // steady state: only the 64 NEW rows (window rows 128..191)
        int prbase = u0m + 128;
        if (prbase >= 192) prbase -= 192;
#pragma unroll
        for (int r = 0; r < 2; r++) {
          int idx = tid + r * 256, lr = idx >> 3, sc = idx & 7;
          gl2lds16(rkb + ((size_t)h * 4096 + U0 + 128 + lr) * 64 + ((sc ^ (lr & 7)) << 3),
                   RKs + (prbase + lr) * 64 + sc * 8);
        }
      }
#pragma unroll
      for (int r = 0; r < 6; r++) {
        int idx = tid + r * 256, row = idx >> 3, sc = idx & 7;
        gl2lds16(vtb + ((size_t)bh * DVC + row) * SEQ + j0 + ((sc ^ (row & 7)) << 3), Vts + idx * 8);
      }
    }
    // wait until only the 6 V loads remain in flight (drains mask+K+RK).
    asm volatile("s_waitcnt vmcnt(6)" ::: "memory");
    __builtin_amdgcn_s_barrier();
    __builtin_amdgcn_sched_barrier(0);
    float mv[4];
#pragma unroll
    for (int st = 0; st < 4; st++) mv[st] = mraw[st] ? 0.f : -1e9f;

#pragma unroll
    for (int s = 0; s < 2; s++) {
      // content logits
      __builtin_amdgcn_s_setprio(1);
      f4v Sf[4];
#pragma unroll
      for (int st = 0; st < 4; st++) {
        Sf[st] = (f4v)0.0f;
#pragma unroll
        for (int kc = 0; kc < 2; kc++) {
          int row = st * 16 + l15;
          hf8v kf = *(const hf8v*)(Kts + row * 64 + ((((kc << 2) | quad) ^ (row & 7)) << 3));
          Sf[st] = mfma16(qf[s][kc], kf, Sf[st]);
        }
      }
      // rel logits over 80-row window (phys rows via rolling base)
      f4v Rf[5];
      const int tb = 112 - 32 * wv - 16 * s;
#pragma unroll
      for (int u = 0; u < 5; u++) {
        int pg = u0m + tb + u * 16;
        if (pg >= 192) pg -= 192;
        Rf[u] = (f4v)0.0f;
#pragma unroll
        for (int kc = 0; kc < 2; kc++) {
          int row = pg + l15;
          hf8v rf = *(const hf8v*)(RKs + row * 64 + ((((kc << 2) | quad) ^ (row & 7)) << 3));
          Rf[u] = mfma16(qbf[s][kc], rf, Rf[u]);
        }
      }
      __builtin_amdgcn_s_setprio(0);
      // band extraction via bpermute: S[r][c] += R[r][c-r+15]
#pragma unroll
      for (int reg = 0; reg < 4; reg++) {
        int delta = l15 - (quad << 2) - reg + 15;  // [0,30]
        int srcl = (quad << 4) | (delta & 15);
        float sh0 = __shfl(Rf[0][reg], srcl, 64);
        float sh1 = __shfl(Rf[1][reg], srcl, 64);
        float sh2 = __shfl(Rf[2][reg], srcl, 64);
        float sh3 = __shfl(Rf[3][reg], srcl, 64);
        float sh4 = __shfl(Rf[4][reg], srcl, 64);
        bool hib = delta >= 16;
        Sf[0][reg] += (hib ? sh1 : sh0) + mv[0];
        Sf[1][reg] += (hib ? sh2 : sh1) + mv[1];
        Sf[2][reg] += (hib ? sh3 : sh2) + mv[2];
        Sf[3][reg] += (hib ? sh4 : sh3) + mv[3];
      }
      // online softmax with defer-max (THR=8): row-max via DPP (VALU, not LDS);
      // rescale only when max grows by >8 -> P bounded by e^8 (fits f16).
#pragma unroll
      for (int reg = 0; reg < 4; reg++) {
        float t = fmaxf(fmaxf(Sf[0][reg], Sf[1][reg]), fmaxf(Sf[2][reg], Sf[3][reg]));
        t = rowmax16(t);
        if (__any(t - m_i[s][reg] > 8.0f)) {
          float mn = fmaxf(m_i[s][reg], t);
          float alpha = __expf(m_i[s][reg] - mn);
          m_i[s][reg] = mn;
          l_i[s][reg] *= alpha;
#pragma unroll
          for (int se = 0; se < 12; se++) Of[s][se][reg] *= alpha;
        }
        float mcur = m_i[s][reg];
        hf4v pv;
        float rs = 0.f;
#pragma unroll
        for (int st = 0; st < 4; st++) {
          float p = __expf(Sf[st][reg] - mcur);
          rs += p;
          pv[st] = (_Float16)p;
        }
        l_i[s][reg] += rs;  // per-lane partial; row-reduce in epilogue
        *(hf4v*)(Pbs + (size_t)(wv * 32 + s * 16 + quad * 4 + reg) * PSTR + l15 * 4) = pv;
      }
    }

    // PV: P A-frags (wave-private LDS, in-order DS), V B-frags from Vts (pi-ordered keys)
    hf8v pa[2][2];
#pragma unroll
    for (int s = 0; s < 2; s++)
#pragma unroll
      for (int kc = 0; kc < 2; kc++)
        pa[s][kc] = *(const hf8v*)(Pbs + (size_t)(wv * 32 + s * 16 + l15) * PSTR +
                                   kc * 32 + quad * 8);
    // drain own V loads; barrier-join makes all waves' V writes visible
    asm volatile("s_waitcnt vmcnt(0)" ::: "memory");
    __builtin_amdgcn_s_barrier();
    __builtin_amdgcn_sched_barrier(0);
    __builtin_amdgcn_s_setprio(1);
#pragma unroll
    for (int se = 0; se < 12; se++) {
#pragma unroll
      for (int kc = 0; kc < 2; kc++) {
        int row = se * 16 + l15;
        hf8v vf = *(const hf8v*)(Vts + row * 64 + ((((kc << 2) | quad) ^ (row & 7)) << 3));
        Of[0][se] = mfma16(pa[0][kc], vf, Of[0][se]);
        Of[1][se] = mfma16(pa[1][kc], vf, Of[1][se]);
      }
    }
    __builtin_amdgcn_s_setprio(0);

    u0m += 64;
    if (u0m >= 192) u0m -= 192;
  }

#pragma unroll
  for (int s = 0; s < 2; s++)
#pragma unroll
    for (int reg = 0; reg < 4; reg++) {
      float ls = l_i[s][reg];
      ls += __shfl_xor(ls, 1);
      ls += __shfl_xor(ls, 2);
      ls += __shfl_xor(ls, 4);
      ls += __shfl_xor(ls, 8);
      int row = i0 + wv * 32 + s * 16 + quad * 4 + reg;
      int rg = b * SEQ + row;
      if constexpr (SPLITKV) {
        float* Op = Opart + ((size_t)(half * 4096 + rg)) * HDV + h * DVC;
#pragma unroll
        for (int se = 0; se < 12; se++) Op[se * 16 + l15] = Of[s][se][reg];
        if (l15 == 0) {
          size_t mlb = (((size_t)half * 4096 + rg) * HN + h) * 2;
          ml[mlb] = m_i[s][reg];
          ml[mlb + 1] = ls;
        }
      } else {
        float inv = 1.0f / ls;
        size_t base2 = (size_t)rg * HDV + h * DVC;
#pragma unroll
        for (int se = 0; se < 12; se++)
          attn_out[base2 + se * 16 + l15] = (_Float16)(Of[s][se][reg] * inv);
      }
    }
}

// ================= combine the two KV halves =================
__global__ __launch_bounds__(256) void combine_kernel(const float* __restrict__ Opart,
                                                      const float* __restrict__ ml,
                                                      _Float16* __restrict__ attn_out) {
  int i4 = blockIdx.x * 256 + threadIdx.x;  // over 4096*384
  int rg = i4 / 384, c4 = (i4 - rg * 384) * 4;
  int h = c4 / DVC;
  size_t mlb0 = ((size_t)rg * HN + h) * 2;
  size_t mlb1 = (((size_t)4096 + rg) * HN + h) * 2;
  float m0 = ml[mlb0], l0 = ml[mlb0 + 1];
  float m1 = ml[mlb1], l1 = ml[mlb1 + 1];
  float M = fmaxf(m0, m1);
  float w0 = __expf(m0 - M), w1 = __expf(m1 - M);
  float inv = 1.0f / (l0 * w0 + l1 * w1);
  float4 O0 = *(const float4*)(Opart + (size_t)rg * HDV + c4);
  float4 O1 = *(const float4*)(Opart + ((size_t)4096 + rg) * HDV + c4);
  _Float16 o[4] = {(_Float16)((O0.x * w0 + O1.x * w1) * inv),
                   (_Float16)((O0.y * w0 + O1.y * w1) * inv),
                   (_Float16)((O0.z * w0 + O1.z * w1) * inv),
                   (_Float16)((O0.w * w0 + O1.w * w1) * inv)};
  *(unsigned long long*)(attn_out + (size_t)rg * HDV + c4) = *(const unsigned long long*)o;
}

extern "C" void kernel_launch(void* const* d_in, const int* in_sizes, int n_in,
                              void* d_out, int out_size, void* d_ws, size_t ws_size,
                              hipStream_t stream) {
  const float* x    = (const float*)d_in[0];
  const int*   mask = (const int*)d_in[1];
  const float* Wq   = (const float*)d_in[2];
  const float* Wk   = (const float*)d_in[3];
  const float* Wv   = (const float*)d_in[4];
  const float* Wr   = (const float*)d_in[5];
  const float* rwb  = (const float*)d_in[6];
  const float* Wo   = (const float*)d_in[7];
  const float* bo   = (const float*)d_in[8];
  float* out = (float*)d_out;

  char* wsb = (char*)d_ws;
  size_t o = 0;
  auto al = [](size_t v) { return (v + 255) & ~(size_t)255; };
#define CARVE(ptr_t, name, bytes) ptr_t name = (ptr_t)(wsb + o); o = al(o + (bytes));
  CARVE(_Float16*, pe_h, (size_t)4096 * 192 * 2)
  CARVE(_Float16*, WrT, (size_t)HDK * 192 * 2)
  CARVE(_Float16*, xb, (size_t)BN * SEQ * CDIM * 2)
  CARVE(_Float16*, WTqkv, (size_t)2560 * CDIM * 2)
  CARVE(_Float16*, WoT, (size_t)HDV * CDIM * 2)
  CARVE(_Float16*, qb, (size_t)BN * SEQ * HDK * 2)
  CARVE(_Float16*, kb, (size_t)BN * SEQ * HDK * 2)
  CARVE(_Float16*, vtb, (size_t)BN * SEQ * HDV * 2)
  CARVE(_Float16*, rkb, (size_t)HN * 4096 * 64 * 2)
  _Float16* attnh = xb;  // xb dead after QKV gemm -> safe alias
  CARVE(float*, Opart, (size_t)2 * 4096 * HDV * 4)
  CARVE(float*, ml, (size_t)2 * 4096 * HN * 2 * 4)
  bool dosplit = (o <= ws_size);

  prep_kernel<<<PREP_BLOCKS, 256, 0, stream>>>(x, Wq, Wk, Wv, Wo, Wr, xb, WTqkv, WoT, WrT,
                                               pe_h);
  mfma_gemm_qkvrk<<<768, 256, 0, stream>>>(xb, WTqkv, pe_h, WrT, qb, kb, vtb, rkb);
  if (dosplit) {
    attn_mfma<true><<<512, 256, 0, stream>>>(qb, kb, vtb, rkb, rwb, mask,
                                             attnh, Opart, ml);
    combine_kernel<<<4096 * 384 / 256, 256, 0, stream>>>(Opart, ml, attnh);
  } else {
    attn_mfma<false><<<256, 256, 0, stream>>>(qb, kb, vtb, rkb, rwb, mask,
                                              attnh, nullptr, nullptr);
  }
  mfma_gemm_out<<<768, 256, 0, stream>>>(attnh, WoT, bo, out);
}